// Round 1
// 156319.849 us; speedup vs baseline: 2.4824x; 2.4824x over previous
//
#include <hip/hip_runtime.h>
#include <hip/hip_bf16.h>

typedef unsigned short u16;

// ---------------- constants ----------------
// B=64, T=512, C=512, H=512, D=80, RF=2, PRE_IN=160, PRE_INNER=256, CONV_CH=32, K=31

__device__ __forceinline__ float b2f(u16 u) {
  return __uint_as_float(((unsigned)u) << 16);
}
__device__ __forceinline__ u16 f2b(float f) {   // RNE f32->bf16
  unsigned u = __float_as_uint(f);
  u += 0x7fffu + ((u >> 16) & 1u);
  return (u16)(u >> 16);
}
// dtype-generic input load / output store (F32: raw f32; else bf16 u16)
template<bool F32>
__device__ __forceinline__ float ldw(const void* p, size_t i) {
  return F32 ? ((const float*)p)[i] : b2f(((const u16*)p)[i]);
}
template<bool F32>
__device__ __forceinline__ void stout(void* p, size_t i, float v) {
  if (F32) ((float*)p)[i] = v; else ((u16*)p)[i] = f2b(v);
}
__device__ __forceinline__ float frcp(float x) { return __builtin_amdgcn_rcpf(x); }
__device__ __forceinline__ float tanh_f(float x) {
  float e = __expf(2.f * x);
  return 1.f - 2.f * frcp(e + 1.f);     // inf-safe
}
__device__ __forceinline__ float sig_f(float x) { return frcp(1.f + __expf(-x)); }

// ---- relaxed agent-scope (MALL-coherent, fence-free) accessors ----
// These lower to sc1-flagged global load/store: visible across XCDs without
// any buffer_wbl2/buffer_inv cache maintenance (the old gridbar's killer).
__device__ __forceinline__ void st_sc(int* p, int v) {
  __hip_atomic_store(p, v, __ATOMIC_RELAXED, __HIP_MEMORY_SCOPE_AGENT);
}
__device__ __forceinline__ int ld_sc(const int* p) {
  return __hip_atomic_load(p, __ATOMIC_RELAXED, __HIP_MEMORY_SCOPE_AGENT);
}
__device__ __forceinline__ void stf_sc(float* p, float v) {
  __hip_atomic_store(p, v, __ATOMIC_RELAXED, __HIP_MEMORY_SCOPE_AGENT);
}
__device__ __forceinline__ float ldf_sc(const float* p) {
  return __hip_atomic_load(p, __ATOMIC_RELAXED, __HIP_MEMORY_SCOPE_AGENT);
}

// ---------------- ws layout (float offsets), ~39.5 MB ----------------
constexpr size_t OBAR  = 0;                       // [32]=gen, [64]=dtype flag
constexpr size_t OFLG  = OBAR  + 128;             // per-wg arrival flags 256*32 ints
constexpr size_t OASUM = OFLG  + 8192;            // att_sum [b][t]     32768
constexpr size_t ODEC  = OASUM + 32768;           // dec    [b][h]      32768
constexpr size_t OH0   = ODEC  + 32768;           // h0T    [h][b]      32768
constexpr size_t OH1   = OH0   + 32768;           // h1T    [h][b]      32768
constexpr size_t OPO   = OH1   + 32768;           // poT    [n][b]      10240
constexpr size_t OZEND = OPO   + 10240;
constexpr int    ZERO_SPAN_N = (int)OZEND;        // 149632
constexpr size_t OPRV  = OZEND;                   // prev_w [b][t]      32768
constexpr size_t OERG  = OPRV  + 32768;           // erg    [b][t]      32768
constexpr size_t OX1   = OERG  + 32768;           // x1T    [n][b]      16384
constexpr size_t OX2   = OX1   + 16384;           // x2T    [n][b]      32768
constexpr size_t OATTC = OX2   + 32768;           // attcT  [c][b]      32768
constexpr size_t OMM   = OATTC + 32768;           // M[h][32] f32       16384
constexpr size_t OGI0  = OMM   + 16384;           // gi0p [4][1536][64] 393216 (setup alias: encT)
constexpr size_t OGH0  = OGI0  + 393216;          // gh0p               196608
constexpr size_t OGH1  = OGH0  + 196608;          // gh1p               196608
constexpr size_t OGI1  = OGH1  + 196608;          // gi1p               393216
constexpr size_t OPM   = OGI1  + 393216;          // pm bf16 (16.7M u16 = 8388608 slots)
constexpr size_t OTOT  = OPM   + 8388608;

// ---------------- fence-free flag barrier ----------------
// Arrival: wg stores target to its own cacheline-spaced flag (relaxed, agent).
// Wave 0 of wg 0 sweeps all 256 flags; on all-arrived it publishes gen.
// Everyone else polls gen. No RMW, no release/acquire fences -> no L2
// writeback/invalidate storms. __syncthreads() before arrival drains each
// wave's vmcnt (compiler-guaranteed), ordering data stores before the flag.
__device__ __forceinline__ void fastbar(int* flags, int* gen, int target,
                                        int wg, int tid) {
  __syncthreads();
  if (tid == 0) st_sc(flags + wg * 32, target);
  if (wg == 0) {
    if (tid < 64) {
      int i0 = tid * 4;
      for (;;) {
        int ok = (ld_sc(flags + (i0 + 0) * 32) >= target)
               & (ld_sc(flags + (i0 + 1) * 32) >= target)
               & (ld_sc(flags + (i0 + 2) * 32) >= target)
               & (ld_sc(flags + (i0 + 3) * 32) >= target);
        if (__ballot(ok) == 0xFFFFFFFFFFFFFFFFull) break;
      }
      if (tid == 0) st_sc(gen, target);
    }
    __syncthreads();
  } else {
    if (tid == 0) {
      while (ld_sc(gen) < target) {}
    }
    __syncthreads();
  }
}

// ---------------- setup kernels ----------------
__global__ void k_zero(float* p, int n) {
  for (int i = blockIdx.x * 256 + threadIdx.x; i < n; i += gridDim.x * 256) p[i] = 0.f;
}
// dtype detector: probe pn_w1. bf16 data -> even-index u16s have sane exponent
// fields; f32 data -> even u16s are mantissa low-halves (uniform garbage).
__global__ void k_detect(int* flag, const u16* probe) {
  if (blockIdx.x != 0 || threadIdx.x != 0) return;
  int sane = 0;
  for (int i = 0; i < 256; i += 2) {
    u16 u = probe[i];
    int e = (u >> 7) & 0xFF;
    if (u == 0 || (e >= 97 && e <= 140)) ++sane;
  }
  *flag = (sane < 96) ? 1 : 0;   // 1 => inputs are raw f32
}
__global__ void k_prevw(float* prevw, const int* dlen) {
  int b = blockIdx.x;
  int len = dlen[b] >> 1;
  float inv = 1.f / (float)len;
  for (int i = threadIdx.x; i < 512; i += 256)
    prevw[b * 512 + i] = (i < len) ? inv : 0.f;
}
// att_enc_w [h][c] -> dst [c][h] f32
template<bool F32>
__global__ void k_cvtT512(const int* flag, float* dst, const void* src) {
  if (*flag != (F32 ? 1 : 0)) return;
  for (int i = blockIdx.x * 256 + threadIdx.x; i < 262144; i += gridDim.x * 256) {
    int c = i >> 9, h = i & 511;
    dst[i] = ldw<F32>(src, (size_t)h * 512 + c);
  }
}
// M[h][k] = sum_c loc_w[h][c] * conv_w[c][0][k]
template<bool F32>
__global__ void k_mmat(const int* flag, float* M, const void* locw, const void* convw) {
  if (*flag != (F32 ? 1 : 0)) return;
  int i = blockIdx.x * 256 + threadIdx.x;
  if (i >= 16384) return;
  int h = i >> 5, k = i & 31;
  float acc = 0.f;
  if (k < 31) {
    for (int c = 0; c < 32; ++c)
      acc = fmaf(ldw<F32>(locw, h * 32 + c), ldw<F32>(convw, c * 31 + k), acc);
  }
  M[i] = acc;
}
// pm[b][t][h] = enc[b][t][:] @ att_enc_w[h][:] + b[h]  (stored bf16)
template<bool F32>
__global__ __launch_bounds__(256) void k_pm(const int* flag, u16* pm, const void* enc,
                                            const float* encwT, const void* encb) {
  if (*flag != (F32 ? 1 : 0)) return;
  __shared__ float encf[16 * 512];
  int row0 = blockIdx.x * 16;
  int tid = threadIdx.x;
  for (int i = tid; i < 16 * 512; i += 256) {
    int r = i >> 9, c = i & 511;
    encf[i] = ldw<F32>(enc, (size_t)(row0 + r) * 512 + c);
  }
  __syncthreads();
  float a0[16], a1[16];
  float bb0 = ldw<F32>(encb, tid), bb1 = ldw<F32>(encb, tid + 256);
#pragma unroll
  for (int r = 0; r < 16; ++r) { a0[r] = bb0; a1[r] = bb1; }
  for (int c = 0; c < 512; ++c) {
    float w0 = encwT[c * 512 + tid];
    float w1 = encwT[c * 512 + 256 + tid];
#pragma unroll
    for (int r = 0; r < 16; ++r) {
      float a = encf[r * 512 + c];
      a0[r] = fmaf(w0, a, a0[r]);
      a1[r] = fmaf(w1, a, a1[r]);
    }
  }
#pragma unroll
  for (int r = 0; r < 16; ++r) {
    pm[(size_t)(row0 + r) * 512 + tid]       = f2b(a0[r]);
    pm[(size_t)(row0 + r) * 512 + 256 + tid] = f2b(a1[r]);
  }
}

// ---------------- main persistent kernel ----------------
struct KP {
  const void* __restrict__ enc;
  const int* __restrict__ dlen;
  const u16* __restrict__ pm;          // internal bf16
  const void* __restrict__ wih0; const void* __restrict__ whh0;
  const void* __restrict__ wih1; const void* __restrict__ whh1;
  const void* __restrict__ adec; const void* __restrict__ outw;
  const void* __restrict__ pnw2; const void* __restrict__ pnw1;
  const void* __restrict__ pnb1; const void* __restrict__ pnb2;
  const void* __restrict__ bih0; const void* __restrict__ bhh0;
  const void* __restrict__ bih1; const void* __restrict__ bhh1;
  const void* __restrict__ outb; const void* __restrict__ vw;
  const float* __restrict__ Mg;
  int* __restrict__ bar;               // [32]=gen, [64]=dtype
  int* __restrict__ flags;             // 256 * 32 ints
  float* __restrict__ asum; float* __restrict__ dec;
  float* __restrict__ h0T;  float* __restrict__ h1T;  float* __restrict__ poT;
  float* __restrict__ prevw; float* __restrict__ erg;
  float* __restrict__ x1T;  float* __restrict__ x2T;  float* __restrict__ attcT;
  float* __restrict__ gi0p; float* __restrict__ gh0p;
  float* __restrict__ gh1p; float* __restrict__ gi1p;
  void* __restrict__ out;              // out_o at elem 0; out_a at elem 5242880
};

template<bool F32>
__global__ __launch_bounds__(256, 1) void k_loop(KP p) {
  if (*(const volatile int*)(p.bar + 64) != (F32 ? 1 : 0)) return;  // wrong-dtype variant exits
  __shared__ u16  M_u[32 * 512];
  __shared__ float dec_s[512];
  __shared__ float v_s[512];
  __shared__ float wq[160];
  __shared__ float sm[512];
  __shared__ float red[8];

  const int wg = blockIdx.x, tid = threadIdx.x;
  const int lane = tid & 63;
  const int wv = __builtin_amdgcn_readfirstlane(tid >> 6);
  const int wflat = wg * 4 + wv;
  const int b_att = wg >> 2, q = wg & 3, t0 = q * 128;
  const int trow = tid >> 6, hcol = tid & 63;
  int* genp = p.bar + 32;
  int bt = 0;

  for (int i = tid; i < 32 * 512; i += 256) {
    int k = i >> 9, h = i & 511;
    M_u[i] = f2b(p.Mg[h * 32 + k]);
  }
  for (int i = tid; i < 512; i += 256) v_s[i] = ldw<F32>(p.vw, i);
  __syncthreads();

  for (int t = 0; t < 512; ++t) {
    // ===== S1: attention energies (+ prenet-1) =====
    if (wg < 64) {
      int n = wg * 4 + wv;
      float a0 = 0.f, a1 = 0.f;
      for (int k = 0; k < 160; k += 2) {
        a0 = fmaf(ldw<F32>(p.pnw1, n * 160 + k),     ldf_sc(p.poT + k * 64 + lane),       a0);
        a1 = fmaf(ldw<F32>(p.pnw1, n * 160 + k + 1), ldf_sc(p.poT + (k + 1) * 64 + lane), a1);
      }
      float a = a0 + a1 + ldw<F32>(p.pnb1, n);
      stf_sc(p.x1T + n * 64 + lane, fmaxf(a, 0.f));
    }
    if (tid < 158) {
      int g = t0 - 15 + tid;
      wq[tid] = (g >= 0 && g < 512) ? ldf_sc(p.prevw + b_att * 512 + g) : 0.f;
    }
    for (int i = tid; i < 512; i += 256) dec_s[i] = ldf_sc(p.dec + b_att * 512 + i);
    __syncthreads();
    {
      float wreg[62];
#pragma unroll
      for (int i = 0; i < 62; ++i) wreg[i] = wq[trow * 32 + i];
      float acc[32];
#pragma unroll
      for (int s = 0; s < 32; ++s) acc[s] = 0.f;
      const u16* pmb = p.pm + ((size_t)(b_att * 512 + t0 + trow * 32)) * 512;
      for (int j = 0; j < 8; ++j) {
        int hj = hcol + 64 * j;
        float Mreg[31];
#pragma unroll
        for (int k = 0; k < 31; ++k) Mreg[k] = b2f(M_u[k * 512 + hj]);
        float dj = dec_s[hj], vj = v_s[hj];
#pragma unroll
        for (int s = 0; s < 32; ++s) {
          float u = dj;
#pragma unroll
          for (int k = 0; k < 31; ++k) u = fmaf(Mreg[k], wreg[s + k], u);
          u += b2f(pmb[s * 512 + hj]);
          acc[s] = fmaf(vj, tanh_f(u), acc[s]);
        }
      }
#pragma unroll
      for (int s = 0; s < 32; ++s) {
        float v = acc[s];
#pragma unroll
        for (int off = 32; off; off >>= 1) v += __shfl_xor(v, off, 64);
        if (hcol == 0) sm[trow * 32 + s] = v;
      }
      __syncthreads();
      if (tid < 128) stf_sc(p.erg + b_att * 512 + t0 + tid, sm[tid]);
    }
    fastbar(p.flags, genp, ++bt, wg, tid);

    // ===== S2: softmax/out_a | att_c | prenet-2 =====
    if (wg < 64) {
      int b = wg;
      int len = p.dlen[b] >> 1;
      float e0 = ldf_sc(p.erg + b * 512 + tid), e1 = ldf_sc(p.erg + b * 512 + 256 + tid);
      bool v0 = tid < len, v1 = (256 + tid) < len;
      float mx = fmaxf(v0 ? e0 : -1e30f, v1 ? e1 : -1e30f);
#pragma unroll
      for (int off = 32; off; off >>= 1) mx = fmaxf(mx, __shfl_xor(mx, off, 64));
      if (lane == 0) red[wv] = mx;
      __syncthreads();
      mx = fmaxf(fmaxf(red[0], red[1]), fmaxf(red[2], red[3]));
      float x0 = v0 ? __expf(e0 - mx) : 0.f;
      float x1 = v1 ? __expf(e1 - mx) : 0.f;
      float s = x0 + x1;
#pragma unroll
      for (int off = 32; off; off >>= 1) s += __shfl_xor(s, off, 64);
      if (lane == 0) red[4 + wv] = s;
      __syncthreads();
      s = red[4] + red[5] + red[6] + red[7];
      float inv = 1.f / s;
      float w0 = x0 * inv, w1 = x1 * inv;
      stout<F32>(p.out, 5242880 + (size_t)b * 262144 + (size_t)tid * 512 + t, w0);
      stout<F32>(p.out, 5242880 + (size_t)b * 262144 + (size_t)(tid + 256) * 512 + t, w1);
      float s0 = p.asum[b * 512 + tid] + w0;
      float s1 = p.asum[b * 512 + 256 + tid] + w1;
      p.asum[b * 512 + tid] = s0;          stf_sc(p.prevw + b * 512 + tid, s0);
      p.asum[b * 512 + 256 + tid] = s1;    stf_sc(p.prevw + b * 512 + 256 + tid, s1);
    } else if (wg < 192) {
      int idx = wg - 64, b = idx >> 1, half = idx & 1;
      int len = p.dlen[b] >> 1;
      float e0 = ldf_sc(p.erg + b * 512 + tid), e1 = ldf_sc(p.erg + b * 512 + 256 + tid);
      bool v0 = tid < len, v1 = (256 + tid) < len;
      float mx = fmaxf(v0 ? e0 : -1e30f, v1 ? e1 : -1e30f);
#pragma unroll
      for (int off = 32; off; off >>= 1) mx = fmaxf(mx, __shfl_xor(mx, off, 64));
      if (lane == 0) red[wv] = mx;
      __syncthreads();
      mx = fmaxf(fmaxf(red[0], red[1]), fmaxf(red[2], red[3]));
      float x0 = v0 ? __expf(e0 - mx) : 0.f;
      float x1 = v1 ? __expf(e1 - mx) : 0.f;
      float s = x0 + x1;
#pragma unroll
      for (int off = 32; off; off >>= 1) s += __shfl_xor(s, off, 64);
      if (lane == 0) red[4 + wv] = s;
      __syncthreads();
      s = red[4] + red[5] + red[6] + red[7];
      float inv = 1.f / s;
      sm[tid] = x0 * inv; sm[256 + tid] = x1 * inv;
      __syncthreads();
      int c = half * 256 + tid;
      size_t eb = (size_t)b * 262144 + c;
      float a0 = 0.f, a1 = 0.f, a2 = 0.f, a3 = 0.f;
      for (int tau = 0; tau < 512; tau += 4) {
        a0 = fmaf(sm[tau],     ldw<F32>(p.enc, eb + (size_t)tau * 512),       a0);
        a1 = fmaf(sm[tau + 1], ldw<F32>(p.enc, eb + (size_t)(tau + 1) * 512), a1);
        a2 = fmaf(sm[tau + 2], ldw<F32>(p.enc, eb + (size_t)(tau + 2) * 512), a2);
        a3 = fmaf(sm[tau + 3], ldw<F32>(p.enc, eb + (size_t)(tau + 3) * 512), a3);
      }
      stf_sc(p.attcT + c * 64 + b, (a0 + a1) + (a2 + a3));
    } else {
      int idx = wg - 192;
      int n0 = (idx * 4 + wv) * 2;
      float a0 = 0.f, a1 = 0.f, c0 = 0.f, c1 = 0.f;
      for (int k = 0; k < 256; k += 2) {
        float x0 = ldf_sc(p.x1T + k * 64 + lane), x1 = ldf_sc(p.x1T + (k + 1) * 64 + lane);
        a0 = fmaf(ldw<F32>(p.pnw2, n0 * 256 + k),           x0, a0);
        a1 = fmaf(ldw<F32>(p.pnw2, n0 * 256 + k + 1),       x1, a1);
        c0 = fmaf(ldw<F32>(p.pnw2, (n0 + 1) * 256 + k),     x0, c0);
        c1 = fmaf(ldw<F32>(p.pnw2, (n0 + 1) * 256 + k + 1), x1, c1);
      }
      float xa = a0 + a1 + ldw<F32>(p.pnb2, n0), xb = c0 + c1 + ldw<F32>(p.pnb2, n0 + 1);
      stf_sc(p.x2T + n0 * 64 + lane,       fmaxf(xa, 0.f));
      stf_sc(p.x2T + (n0 + 1) * 64 + lane, fmaxf(xb, 0.f));
    }
    fastbar(p.flags, genp, ++bt, wg, tid);

    // ===== S3: gi0 | gh0 | gh1 =====
    {
      int w = wflat;
      if (w < 512) {
        int kpart = w & 3, n0 = (w >> 2) * 12;
        const float* AT = (kpart < 2) ? p.x2T : p.attcT;
        int k0 = (kpart & 1) * 256;
        size_t wofs = (size_t)(kpart >> 1) * 512;
        float acc[12];
#pragma unroll
        for (int i = 0; i < 12; ++i) acc[i] = 0.f;
        for (int k = k0; k < k0 + 256; ++k) {
          float a = ldf_sc(AT + k * 64 + lane);
#pragma unroll
          for (int i = 0; i < 12; ++i)
            acc[i] = fmaf(ldw<F32>(p.wih0, (size_t)(n0 + i) * 1024 + wofs + k), a, acc[i]);
        }
#pragma unroll
        for (int i = 0; i < 12; ++i)
          stf_sc(p.gi0p + ((size_t)kpart * 1536 + n0 + i) * 64 + lane, acc[i]);
      } else if (w < 768) {
        int u = w - 512; int kpart = u & 1, n0 = (u >> 1) * 12, k0 = kpart * 256;
        float acc[12];
#pragma unroll
        for (int i = 0; i < 12; ++i) acc[i] = 0.f;
        for (int k = k0; k < k0 + 256; ++k) {
          float a = ldf_sc(p.h0T + k * 64 + lane);
#pragma unroll
          for (int i = 0; i < 12; ++i)
            acc[i] = fmaf(ldw<F32>(p.whh0, (size_t)(n0 + i) * 512 + k), a, acc[i]);
        }
#pragma unroll
        for (int i = 0; i < 12; ++i)
          stf_sc(p.gh0p + ((size_t)kpart * 1536 + n0 + i) * 64 + lane, acc[i]);
      } else {
        int u = w - 768; int kpart = u & 1, n0 = (u >> 1) * 12, k0 = kpart * 256;
        float acc[12];
#pragma unroll
        for (int i = 0; i < 12; ++i) acc[i] = 0.f;
        for (int k = k0; k < k0 + 256; ++k) {
          float a = ldf_sc(p.h1T + k * 64 + lane);
#pragma unroll
          for (int i = 0; i < 12; ++i)
            acc[i] = fmaf(ldw<F32>(p.whh1, (size_t)(n0 + i) * 512 + k), a, acc[i]);
        }
#pragma unroll
        for (int i = 0; i < 12; ++i)
          stf_sc(p.gh1p + ((size_t)kpart * 1536 + n0 + i) * 64 + lane, acc[i]);
      }
    }
    fastbar(p.flags, genp, ++bt, wg, tid);

    // ===== S4: GRU0 combine -> h0' =====
    if (wg < 128) {
      int e = wg * 256 + tid;
      int h = e >> 6, b = e & 63;
      float ir = ldf_sc(p.gi0p + h * 64 + b) + ldf_sc(p.gi0p + (1536 + h) * 64 + b)
               + ldf_sc(p.gi0p + (3072 + h) * 64 + b) + ldf_sc(p.gi0p + (4608 + h) * 64 + b)
               + ldw<F32>(p.bih0, h);
      float iz = ldf_sc(p.gi0p + (512 + h) * 64 + b) + ldf_sc(p.gi0p + (2048 + h) * 64 + b)
               + ldf_sc(p.gi0p + (3584 + h) * 64 + b) + ldf_sc(p.gi0p + (5120 + h) * 64 + b)
               + ldw<F32>(p.bih0, 512 + h);
      float in = ldf_sc(p.gi0p + (1024 + h) * 64 + b) + ldf_sc(p.gi0p + (2560 + h) * 64 + b)
               + ldf_sc(p.gi0p + (4096 + h) * 64 + b) + ldf_sc(p.gi0p + (5632 + h) * 64 + b)
               + ldw<F32>(p.bih0, 1024 + h);
      float hr = ldf_sc(p.gh0p + h * 64 + b) + ldf_sc(p.gh0p + (1536 + h) * 64 + b)
               + ldw<F32>(p.bhh0, h);
      float hz = ldf_sc(p.gh0p + (512 + h) * 64 + b) + ldf_sc(p.gh0p + (2048 + h) * 64 + b)
               + ldw<F32>(p.bhh0, 512 + h);
      float hn = ldf_sc(p.gh0p + (1024 + h) * 64 + b) + ldf_sc(p.gh0p + (2560 + h) * 64 + b)
               + ldw<F32>(p.bhh0, 1024 + h);
      float r = sig_f(ir + hr), z = sig_f(iz + hz);
      float nn = tanh_f(in + r * hn);
      float ho = ldf_sc(p.h0T + h * 64 + b);
      stf_sc(p.h0T + h * 64 + b, (1.f - z) * nn + z * ho);
    }
    fastbar(p.flags, genp, ++bt, wg, tid);

    // ===== S5: gi1 | dec_next =====
    {
      int w = wflat;
      if (w < 512) {
        int kpart = w & 3, n0 = (w >> 2) * 12, k0 = kpart * 128;
        float acc[12];
#pragma unroll
        for (int i = 0; i < 12; ++i) acc[i] = 0.f;
        for (int k = k0; k < k0 + 128; ++k) {
          float a = ldf_sc(p.h0T + k * 64 + lane);
#pragma unroll
          for (int i = 0; i < 12; ++i)
            acc[i] = fmaf(ldw<F32>(p.wih1, (size_t)(n0 + i) * 512 + k), a, acc[i]);
        }
#pragma unroll
        for (int i = 0; i < 12; ++i)
          stf_sc(p.gi1p + ((size_t)kpart * 1536 + n0 + i) * 64 + lane, acc[i]);
      } else if (w < 768) {
        int u = w - 512, n0 = u * 2;
        float a0 = 0.f, a1 = 0.f, c0 = 0.f, c1 = 0.f;
        for (int k = 0; k < 512; k += 2) {
          float x0 = ldf_sc(p.h0T + k * 64 + lane), x1 = ldf_sc(p.h0T + (k + 1) * 64 + lane);
          a0 = fmaf(ldw<F32>(p.adec, (size_t)n0 * 512 + k),           x0, a0);
          a1 = fmaf(ldw<F32>(p.adec, (size_t)n0 * 512 + k + 1),       x1, a1);
          c0 = fmaf(ldw<F32>(p.adec, (size_t)(n0 + 1) * 512 + k),     x0, c0);
          c1 = fmaf(ldw<F32>(p.adec, (size_t)(n0 + 1) * 512 + k + 1), x1, c1);
        }
        stf_sc(p.dec + lane * 512 + n0,     a0 + a1);
        stf_sc(p.dec + lane * 512 + n0 + 1, c0 + c1);
      }
    }
    fastbar(p.flags, genp, ++bt, wg, tid);

    // ===== S6: GRU1 combine -> h1' =====
    if (wg < 128) {
      int e = wg * 256 + tid;
      int h = e >> 6, b = e & 63;
      float ir = ldf_sc(p.gi1p + h * 64 + b) + ldf_sc(p.gi1p + (1536 + h) * 64 + b)
               + ldf_sc(p.gi1p + (3072 + h) * 64 + b) + ldf_sc(p.gi1p + (4608 + h) * 64 + b)
               + ldw<F32>(p.bih1, h);
      float iz = ldf_sc(p.gi1p + (512 + h) * 64 + b) + ldf_sc(p.gi1p + (2048 + h) * 64 + b)
               + ldf_sc(p.gi1p + (3584 + h) * 64 + b) + ldf_sc(p.gi1p + (5120 + h) * 64 + b)
               + ldw<F32>(p.bih1, 512 + h);
      float in = ldf_sc(p.gi1p + (1024 + h) * 64 + b) + ldf_sc(p.gi1p + (2560 + h) * 64 + b)
               + ldf_sc(p.gi1p + (4096 + h) * 64 + b) + ldf_sc(p.gi1p + (5632 + h) * 64 + b)
               + ldw<F32>(p.bih1, 1024 + h);
      float hr = ldf_sc(p.gh1p + h * 64 + b) + ldf_sc(p.gh1p + (1536 + h) * 64 + b)
               + ldw<F32>(p.bhh1, h);
      float hz = ldf_sc(p.gh1p + (512 + h) * 64 + b) + ldf_sc(p.gh1p + (2048 + h) * 64 + b)
               + ldw<F32>(p.bhh1, 512 + h);
      float hn = ldf_sc(p.gh1p + (1024 + h) * 64 + b) + ldf_sc(p.gh1p + (2560 + h) * 64 + b)
               + ldw<F32>(p.bhh1, 1024 + h);
      float r = sig_f(ir + hr), z = sig_f(iz + hz);
      float nn = tanh_f(in + r * hn);
      float ho = ldf_sc(p.h1T + h * 64 + b);
      stf_sc(p.h1T + h * 64 + b, (1.f - z) * nn + z * ho);
    }
    fastbar(p.flags, genp, ++bt, wg, tid);

    // ===== S7: out = Wout @ [h1' ; att_c] + b =====
    if (wflat < 160) {
      int n = wflat;
      size_t wr = (size_t)n * 1024;
      float a0 = 0.f, a1 = 0.f, a2 = 0.f, a3 = 0.f;
      for (int k = 0; k < 512; k += 2) {
        a0 = fmaf(ldw<F32>(p.outw, wr + k),           ldf_sc(p.h1T + k * 64 + lane),         a0);
        a1 = fmaf(ldw<F32>(p.outw, wr + k + 1),       ldf_sc(p.h1T + (k + 1) * 64 + lane),   a1);
        a2 = fmaf(ldw<F32>(p.outw, wr + 512 + k),     ldf_sc(p.attcT + k * 64 + lane),       a2);
        a3 = fmaf(ldw<F32>(p.outw, wr + 512 + k + 1), ldf_sc(p.attcT + (k + 1) * 64 + lane), a3);
      }
      float acc = (a0 + a1) + (a2 + a3) + ldw<F32>(p.outb, n);
      stf_sc(p.poT + n * 64 + lane, acc);
      stout<F32>(p.out, (size_t)lane * 81920 + (size_t)(n >> 1) * 1024 + t * 2 + (n & 1), acc);
    }
    fastbar(p.flags, genp, ++bt, wg, tid);
  }
}

// ---------------- host launcher ----------------
extern "C" void kernel_launch(void* const* d_in, const int* in_sizes, int n_in,
                              void* d_out, int out_size, void* d_ws, size_t ws_size,
                              hipStream_t stream) {
  (void)in_sizes; (void)n_in; (void)out_size; (void)ws_size;
  const void* enc   = d_in[0];
  const int*  dlen  = (const int*)d_in[1];
  const void* pnw1  = d_in[2];
  const void* pnb1  = d_in[3];
  const void* pnw2  = d_in[4];
  const void* pnb2  = d_in[5];
  const void* aencw = d_in[6];
  const void* aencb = d_in[7];
  const void* adecw = d_in[8];
  const void* aconv = d_in[9];
  const void* alocw = d_in[10];
  const void* avw   = d_in[11];
  // d_in[12] = att_v_b: softmax-invariant -> unused
  const void* wih0  = d_in[13];
  const void* whh0  = d_in[14];
  const void* bih0  = d_in[15];
  const void* bhh0  = d_in[16];
  const void* wih1  = d_in[17];
  const void* whh1  = d_in[18];
  const void* bih1  = d_in[19];
  const void* bhh1  = d_in[20];
  const void* outw  = d_in[21];
  const void* outb  = d_in[22];

  float* W = (float*)d_ws;
  int* flag = (int*)(W + OBAR) + 64;
  dim3 blk(256);

  k_zero<<<256, blk, 0, stream>>>(W + OBAR, ZERO_SPAN_N);
  k_detect<<<1, blk, 0, stream>>>(flag, (const u16*)pnw1);
  k_prevw<<<64, blk, 0, stream>>>(W + OPRV, dlen);
  // dual-dtype setup (wrong variant self-disables via flag)
  k_mmat<false><<<64, blk, 0, stream>>>(flag, W + OMM, alocw, aconv);
  k_mmat<true ><<<64, blk, 0, stream>>>(flag, W + OMM, alocw, aconv);
  k_cvtT512<false><<<512, blk, 0, stream>>>(flag, W + OGI0, aencw);
  k_cvtT512<true ><<<512, blk, 0, stream>>>(flag, W + OGI0, aencw);
  k_pm<false><<<2048, blk, 0, stream>>>(flag, (u16*)(W + OPM), enc, W + OGI0, aencb);
  k_pm<true ><<<2048, blk, 0, stream>>>(flag, (u16*)(W + OPM), enc, W + OGI0, aencb);

  KP kp;
  kp.enc = enc; kp.dlen = dlen;
  kp.pm = (const u16*)(W + OPM);
  kp.wih0 = wih0; kp.whh0 = whh0;
  kp.wih1 = wih1; kp.whh1 = whh1;
  kp.adec = adecw; kp.outw = outw;
  kp.pnw2 = pnw2; kp.pnw1 = pnw1;
  kp.pnb1 = pnb1; kp.pnb2 = pnb2;
  kp.bih0 = bih0; kp.bhh0 = bhh0;
  kp.bih1 = bih1; kp.bhh1 = bhh1;
  kp.outb = outb; kp.vw = avw;
  kp.Mg = W + OMM;
  kp.bar = (int*)(W + OBAR);
  kp.flags = (int*)(W + OFLG);
  kp.asum = W + OASUM; kp.dec = W + ODEC;
  kp.h0T = W + OH0; kp.h1T = W + OH1; kp.poT = W + OPO;
  kp.prevw = W + OPRV; kp.erg = W + OERG;
  kp.x1T = W + OX1; kp.x2T = W + OX2; kp.attcT = W + OATTC;
  kp.gi0p = W + OGI0; kp.gh0p = W + OGH0;
  kp.gh1p = W + OGH1; kp.gi1p = W + OGI1;
  kp.out = d_out;

  // both variants launched; the wrong-dtype one exits before touching the barrier
  k_loop<false><<<dim3(256), blk, 0, stream>>>(kp);
  k_loop<true ><<<dim3(256), blk, 0, stream>>>(kp);
}

// Round 2
// 120695.740 us; speedup vs baseline: 3.2151x; 1.2952x over previous
//
#include <hip/hip_runtime.h>
#include <hip/hip_bf16.h>

typedef unsigned short u16;

// ---------------- constants ----------------
// B=64, T=512, C=512, H=512, D=80, RF=2, PRE_IN=160, PRE_INNER=256, CONV_CH=32, K=31

__device__ __forceinline__ float b2f(u16 u) {
  return __uint_as_float(((unsigned)u) << 16);
}
__device__ __forceinline__ u16 f2b(float f) {   // RNE f32->bf16
  unsigned u = __float_as_uint(f);
  u += 0x7fffu + ((u >> 16) & 1u);
  return (u16)(u >> 16);
}
// dtype-generic input load / output store (F32: raw f32; else bf16 u16)
template<bool F32>
__device__ __forceinline__ float ldw(const void* p, size_t i) {
  return F32 ? ((const float*)p)[i] : b2f(((const u16*)p)[i]);
}
template<bool F32>
__device__ __forceinline__ void stout(void* p, size_t i, float v) {
  if (F32) ((float*)p)[i] = v; else ((u16*)p)[i] = f2b(v);
}
__device__ __forceinline__ float frcp(float x) { return __builtin_amdgcn_rcpf(x); }
__device__ __forceinline__ float tanh_f(float x) {
  float e = __expf(2.f * x);
  return 1.f - 2.f * frcp(e + 1.f);     // inf-safe
}
__device__ __forceinline__ float sig_f(float x) { return frcp(1.f + __expf(-x)); }

// ---- relaxed agent-scope (MALL-coherent, fence-free) accessors ----
__device__ __forceinline__ void st_sc(int* p, int v) {
  __hip_atomic_store(p, v, __ATOMIC_RELAXED, __HIP_MEMORY_SCOPE_AGENT);
}
__device__ __forceinline__ int ld_sc(const int* p) {
  return __hip_atomic_load(p, __ATOMIC_RELAXED, __HIP_MEMORY_SCOPE_AGENT);
}
__device__ __forceinline__ void stf_sc(float* p, float v) {
  __hip_atomic_store(p, v, __ATOMIC_RELAXED, __HIP_MEMORY_SCOPE_AGENT);
}
__device__ __forceinline__ float ldf_sc(const float* p) {
  return __hip_atomic_load(p, __ATOMIC_RELAXED, __HIP_MEMORY_SCOPE_AGENT);
}

// Burst-copy n floats (n multiple of 2048) global->LDS with 16 (or 8) loads
// in flight per thread: one vmcnt drain per group instead of one per load.
__device__ __forceinline__ void stage_n(float* lds, const float* src, int n, int tid) {
  int i = 0;
  for (; i + 4096 <= n; i += 4096) {
    float r[16];
#pragma unroll
    for (int j = 0; j < 16; ++j) r[j] = ldf_sc(src + i + tid + j * 256);
#pragma unroll
    for (int j = 0; j < 16; ++j) lds[i + tid + j * 256] = r[j];
  }
  for (; i < n; i += 2048) {
    float r[8];
#pragma unroll
    for (int j = 0; j < 8; ++j) r[j] = ldf_sc(src + i + tid + j * 256);
#pragma unroll
    for (int j = 0; j < 8; ++j) lds[i + tid + j * 256] = r[j];
  }
}

// ---------------- ws layout (float offsets), ~39.5 MB ----------------
constexpr size_t OBAR  = 0;                       // [32]=gen, [64]=dtype flag
constexpr size_t OFLG  = OBAR  + 128;             // per-wg arrival flags 256*32 ints
constexpr size_t OASUM = OFLG  + 8192;            // att_sum [b][t]     32768
constexpr size_t ODEC  = OASUM + 32768;           // dec    [b][h]      32768
constexpr size_t OH0   = ODEC  + 32768;           // h0T    [h][b]      32768
constexpr size_t OH1   = OH0   + 32768;           // h1T    [h][b]      32768
constexpr size_t OPO   = OH1   + 32768;           // poT    [n][b]      10240
constexpr size_t OZEND = OPO   + 10240;
constexpr int    ZERO_SPAN_N = (int)OZEND;
constexpr size_t OPRV  = OZEND;                   // prev_w [b][t]      32768
constexpr size_t OERG  = OPRV  + 32768;           // erg    [b][t]      32768
constexpr size_t OX1   = OERG  + 32768;           // x1T    [n][b]      16384
constexpr size_t OX2   = OX1   + 16384;           // x2T    [n][b]      32768
constexpr size_t OATTC = OX2   + 32768;           // attcT  [c][b]      32768
constexpr size_t OMM   = OATTC + 32768;           // M[h][32] f32       16384
constexpr size_t OGI0  = OMM   + 16384;           // gi0p [4][1536][64] 393216 (setup alias: encT)
constexpr size_t OGH0  = OGI0  + 393216;          // gh0p               196608
constexpr size_t OGH1  = OGH0  + 196608;          // gh1p               196608
constexpr size_t OGI1  = OGH1  + 196608;          // gi1p               393216
constexpr size_t OPM   = OGI1  + 393216;          // pm bf16 (16.7M u16 = 8388608 slots)
constexpr size_t OTOT  = OPM   + 8388608;

// ---------------- fence-free flag barrier ----------------
__device__ __forceinline__ void fastbar(int* flags, int* gen, int target,
                                        int wg, int tid) {
  __syncthreads();
  if (tid == 0) st_sc(flags + wg * 32, target);
  if (wg == 0) {
    if (tid < 64) {
      int i0 = tid * 4;
      for (;;) {
        int ok = (ld_sc(flags + (i0 + 0) * 32) >= target)
               & (ld_sc(flags + (i0 + 1) * 32) >= target)
               & (ld_sc(flags + (i0 + 2) * 32) >= target)
               & (ld_sc(flags + (i0 + 3) * 32) >= target);
        if (__ballot(ok) == 0xFFFFFFFFFFFFFFFFull) break;
      }
      if (tid == 0) st_sc(gen, target);
    }
    __syncthreads();
  } else {
    if (tid == 0) {
      while (ld_sc(gen) < target) {}
    }
    __syncthreads();
  }
}

// ---------------- setup kernels ----------------
__global__ void k_zero(float* p, int n) {
  for (int i = blockIdx.x * 256 + threadIdx.x; i < n; i += gridDim.x * 256) p[i] = 0.f;
}
__global__ void k_detect(int* flag, const u16* probe) {
  if (blockIdx.x != 0 || threadIdx.x != 0) return;
  int sane = 0;
  for (int i = 0; i < 256; i += 2) {
    u16 u = probe[i];
    int e = (u >> 7) & 0xFF;
    if (u == 0 || (e >= 97 && e <= 140)) ++sane;
  }
  *flag = (sane < 96) ? 1 : 0;   // 1 => inputs are raw f32
}
__global__ void k_prevw(float* prevw, const int* dlen) {
  int b = blockIdx.x;
  int len = dlen[b] >> 1;
  float inv = 1.f / (float)len;
  for (int i = threadIdx.x; i < 512; i += 256)
    prevw[b * 512 + i] = (i < len) ? inv : 0.f;
}
template<bool F32>
__global__ void k_cvtT512(const int* flag, float* dst, const void* src) {
  if (*flag != (F32 ? 1 : 0)) return;
  for (int i = blockIdx.x * 256 + threadIdx.x; i < 262144; i += gridDim.x * 256) {
    int c = i >> 9, h = i & 511;
    dst[i] = ldw<F32>(src, (size_t)h * 512 + c);
  }
}
template<bool F32>
__global__ void k_mmat(const int* flag, float* M, const void* locw, const void* convw) {
  if (*flag != (F32 ? 1 : 0)) return;
  int i = blockIdx.x * 256 + threadIdx.x;
  if (i >= 16384) return;
  int h = i >> 5, k = i & 31;
  float acc = 0.f;
  if (k < 31) {
    for (int c = 0; c < 32; ++c)
      acc = fmaf(ldw<F32>(locw, h * 32 + c), ldw<F32>(convw, c * 31 + k), acc);
  }
  M[i] = acc;
}
template<bool F32>
__global__ __launch_bounds__(256) void k_pm(const int* flag, u16* pm, const void* enc,
                                            const float* encwT, const void* encb) {
  if (*flag != (F32 ? 1 : 0)) return;
  __shared__ float encf[16 * 512];
  int row0 = blockIdx.x * 16;
  int tid = threadIdx.x;
  for (int i = tid; i < 16 * 512; i += 256) {
    int r = i >> 9, c = i & 511;
    encf[i] = ldw<F32>(enc, (size_t)(row0 + r) * 512 + c);
  }
  __syncthreads();
  float a0[16], a1[16];
  float bb0 = ldw<F32>(encb, tid), bb1 = ldw<F32>(encb, tid + 256);
#pragma unroll
  for (int r = 0; r < 16; ++r) { a0[r] = bb0; a1[r] = bb1; }
  for (int c = 0; c < 512; ++c) {
    float w0 = encwT[c * 512 + tid];
    float w1 = encwT[c * 512 + 256 + tid];
#pragma unroll
    for (int r = 0; r < 16; ++r) {
      float a = encf[r * 512 + c];
      a0[r] = fmaf(w0, a, a0[r]);
      a1[r] = fmaf(w1, a, a1[r]);
    }
  }
#pragma unroll
  for (int r = 0; r < 16; ++r) {
    pm[(size_t)(row0 + r) * 512 + tid]       = f2b(a0[r]);
    pm[(size_t)(row0 + r) * 512 + 256 + tid] = f2b(a1[r]);
  }
}

// ---------------- main persistent kernel ----------------
struct KP {
  const void* __restrict__ enc;
  const int* __restrict__ dlen;
  const u16* __restrict__ pm;          // internal bf16
  const void* __restrict__ wih0; const void* __restrict__ whh0;
  const void* __restrict__ wih1; const void* __restrict__ whh1;
  const void* __restrict__ adec; const void* __restrict__ outw;
  const void* __restrict__ pnw2; const void* __restrict__ pnw1;
  const void* __restrict__ pnb1; const void* __restrict__ pnb2;
  const void* __restrict__ bih0; const void* __restrict__ bhh0;
  const void* __restrict__ bih1; const void* __restrict__ bhh1;
  const void* __restrict__ outb; const void* __restrict__ vw;
  const float* __restrict__ Mg;
  int* __restrict__ bar;               // [32]=gen, [64]=dtype
  int* __restrict__ flags;             // 256 * 32 ints
  float* __restrict__ asum; float* __restrict__ dec;
  float* __restrict__ h0T;  float* __restrict__ h1T;  float* __restrict__ poT;
  float* __restrict__ prevw; float* __restrict__ erg;
  float* __restrict__ x1T;  float* __restrict__ x2T;  float* __restrict__ attcT;
  float* __restrict__ gi0p; float* __restrict__ gh0p;
  float* __restrict__ gh1p; float* __restrict__ gi1p;
  void* __restrict__ out;              // out_o at elem 0; out_a at elem 5242880
};

template<bool F32>
__global__ __launch_bounds__(256, 1) void k_loop(KP p) {
  if (*(const volatile int*)(p.bar + 64) != (F32 ? 1 : 0)) return;  // wrong-dtype variant exits
  __shared__ float stg[16384];       // 64 KB activation staging buffer
  __shared__ u16  M_u[32 * 512];
  __shared__ float dec_s[512];
  __shared__ float v_s[512];
  __shared__ float wq[160];
  __shared__ float sm[512];
  __shared__ float red[8];

  const int wg = blockIdx.x, tid = threadIdx.x;
  const int lane = tid & 63;
  const int wv = __builtin_amdgcn_readfirstlane(tid >> 6);
  const int wflat = wg * 4 + wv;
  const int b_att = wg >> 2, q = wg & 3, t0 = q * 128;
  const int trow = tid >> 6, hcol = tid & 63;
  int* genp = p.bar + 32;
  int bt = 0;

  for (int i = tid; i < 32 * 512; i += 256) {
    int k = i >> 9, h = i & 511;
    M_u[i] = f2b(p.Mg[h * 32 + k]);
  }
  for (int i = tid; i < 512; i += 256) v_s[i] = ldw<F32>(p.vw, i);
  __syncthreads();

  for (int t = 0; t < 512; ++t) {
    // ===== S1: attention energies (+ prenet-1 from LDS-staged poT) =====
    if (wg < 64) stage_n(stg, p.poT, 10240, tid);   // poT [160][64] shared by 4 waves
    if (tid < 158) {
      int g = t0 - 15 + tid;
      wq[tid] = (g >= 0 && g < 512) ? ldf_sc(p.prevw + b_att * 512 + g) : 0.f;
    }
    for (int i = tid; i < 512; i += 256) dec_s[i] = ldf_sc(p.dec + b_att * 512 + i);
    __syncthreads();
    if (wg < 64) {
      int n = wg * 4 + wv;
      float a = ldw<F32>(p.pnb1, n);
      for (int k = 0; k < 160; ++k)
        a = fmaf(ldw<F32>(p.pnw1, n * 160 + k), stg[k * 64 + lane], a);
      stf_sc(p.x1T + n * 64 + lane, fmaxf(a, 0.f));
    }
    {
      float wreg[62];
#pragma unroll
      for (int i = 0; i < 62; ++i) wreg[i] = wq[trow * 32 + i];
      float acc[32];
#pragma unroll
      for (int s = 0; s < 32; ++s) acc[s] = 0.f;
      const u16* pmb = p.pm + ((size_t)(b_att * 512 + t0 + trow * 32)) * 512;
      for (int j = 0; j < 8; ++j) {
        int hj = hcol + 64 * j;
        float Mreg[31];
#pragma unroll
        for (int k = 0; k < 31; ++k) Mreg[k] = b2f(M_u[k * 512 + hj]);
        float dj = dec_s[hj], vj = v_s[hj];
#pragma unroll
        for (int s = 0; s < 32; ++s) {
          float u = dj;
#pragma unroll
          for (int k = 0; k < 31; ++k) u = fmaf(Mreg[k], wreg[s + k], u);
          u += b2f(pmb[s * 512 + hj]);
          acc[s] = fmaf(vj, tanh_f(u), acc[s]);
        }
      }
#pragma unroll
      for (int s = 0; s < 32; ++s) {
        float v = acc[s];
#pragma unroll
        for (int off = 32; off; off >>= 1) v += __shfl_xor(v, off, 64);
        if (hcol == 0) sm[trow * 32 + s] = v;
      }
      __syncthreads();
      if (tid < 128) stf_sc(p.erg + b_att * 512 + t0 + tid, sm[tid]);
    }
    fastbar(p.flags, genp, ++bt, wg, tid);

    // ===== S2: softmax/out_a | att_c | prenet-2 =====
    if (wg < 64) {
      int b = wg;
      int len = p.dlen[b] >> 1;
      float e0 = ldf_sc(p.erg + b * 512 + tid), e1 = ldf_sc(p.erg + b * 512 + 256 + tid);
      bool v0 = tid < len, v1 = (256 + tid) < len;
      float mx = fmaxf(v0 ? e0 : -1e30f, v1 ? e1 : -1e30f);
#pragma unroll
      for (int off = 32; off; off >>= 1) mx = fmaxf(mx, __shfl_xor(mx, off, 64));
      if (lane == 0) red[wv] = mx;
      __syncthreads();
      mx = fmaxf(fmaxf(red[0], red[1]), fmaxf(red[2], red[3]));
      float x0 = v0 ? __expf(e0 - mx) : 0.f;
      float x1 = v1 ? __expf(e1 - mx) : 0.f;
      float s = x0 + x1;
#pragma unroll
      for (int off = 32; off; off >>= 1) s += __shfl_xor(s, off, 64);
      if (lane == 0) red[4 + wv] = s;
      __syncthreads();
      s = red[4] + red[5] + red[6] + red[7];
      float inv = 1.f / s;
      float w0 = x0 * inv, w1 = x1 * inv;
      stout<F32>(p.out, 5242880 + (size_t)b * 262144 + (size_t)tid * 512 + t, w0);
      stout<F32>(p.out, 5242880 + (size_t)b * 262144 + (size_t)(tid + 256) * 512 + t, w1);
      float s0 = p.asum[b * 512 + tid] + w0;
      float s1 = p.asum[b * 512 + 256 + tid] + w1;
      p.asum[b * 512 + tid] = s0;          stf_sc(p.prevw + b * 512 + tid, s0);
      p.asum[b * 512 + 256 + tid] = s1;    stf_sc(p.prevw + b * 512 + 256 + tid, s1);
    } else if (wg < 192) {
      int idx = wg - 64, b = idx >> 1, half = idx & 1;
      int len = p.dlen[b] >> 1;
      float e0 = ldf_sc(p.erg + b * 512 + tid), e1 = ldf_sc(p.erg + b * 512 + 256 + tid);
      bool v0 = tid < len, v1 = (256 + tid) < len;
      float mx = fmaxf(v0 ? e0 : -1e30f, v1 ? e1 : -1e30f);
#pragma unroll
      for (int off = 32; off; off >>= 1) mx = fmaxf(mx, __shfl_xor(mx, off, 64));
      if (lane == 0) red[wv] = mx;
      __syncthreads();
      mx = fmaxf(fmaxf(red[0], red[1]), fmaxf(red[2], red[3]));
      float x0 = v0 ? __expf(e0 - mx) : 0.f;
      float x1 = v1 ? __expf(e1 - mx) : 0.f;
      float s = x0 + x1;
#pragma unroll
      for (int off = 32; off; off >>= 1) s += __shfl_xor(s, off, 64);
      if (lane == 0) red[4 + wv] = s;
      __syncthreads();
      s = red[4] + red[5] + red[6] + red[7];
      float inv = 1.f / s;
      sm[tid] = x0 * inv; sm[256 + tid] = x1 * inv;
      __syncthreads();
      int c = half * 256 + tid;
      size_t eb = (size_t)b * 262144 + c;
      float a0 = 0.f, a1 = 0.f, a2 = 0.f, a3 = 0.f;
      float a4 = 0.f, a5 = 0.f, a6 = 0.f, a7 = 0.f;
      for (int tau = 0; tau < 512; tau += 8) {   // 8 chains: deeper VMEM pipeline
        a0 = fmaf(sm[tau],     ldw<F32>(p.enc, eb + (size_t)tau * 512),       a0);
        a1 = fmaf(sm[tau + 1], ldw<F32>(p.enc, eb + (size_t)(tau + 1) * 512), a1);
        a2 = fmaf(sm[tau + 2], ldw<F32>(p.enc, eb + (size_t)(tau + 2) * 512), a2);
        a3 = fmaf(sm[tau + 3], ldw<F32>(p.enc, eb + (size_t)(tau + 3) * 512), a3);
        a4 = fmaf(sm[tau + 4], ldw<F32>(p.enc, eb + (size_t)(tau + 4) * 512), a4);
        a5 = fmaf(sm[tau + 5], ldw<F32>(p.enc, eb + (size_t)(tau + 5) * 512), a5);
        a6 = fmaf(sm[tau + 6], ldw<F32>(p.enc, eb + (size_t)(tau + 6) * 512), a6);
        a7 = fmaf(sm[tau + 7], ldw<F32>(p.enc, eb + (size_t)(tau + 7) * 512), a7);
      }
      stf_sc(p.attcT + c * 64 + b, ((a0 + a1) + (a2 + a3)) + ((a4 + a5) + (a6 + a7)));
    } else {
      stage_n(stg, p.x1T, 16384, tid);           // x1T [256][64] shared by 4 waves
      __syncthreads();
      int idx = wg - 192;
      int n0 = (idx * 4 + wv) * 2;
      float a0 = 0.f, a1 = 0.f, c0 = 0.f, c1 = 0.f;
      for (int k = 0; k < 256; k += 2) {
        float x0 = stg[k * 64 + lane], x1 = stg[(k + 1) * 64 + lane];
        a0 = fmaf(ldw<F32>(p.pnw2, n0 * 256 + k),           x0, a0);
        a1 = fmaf(ldw<F32>(p.pnw2, n0 * 256 + k + 1),       x1, a1);
        c0 = fmaf(ldw<F32>(p.pnw2, (n0 + 1) * 256 + k),     x0, c0);
        c1 = fmaf(ldw<F32>(p.pnw2, (n0 + 1) * 256 + k + 1), x1, c1);
      }
      float xa = a0 + a1 + ldw<F32>(p.pnb2, n0), xb = c0 + c1 + ldw<F32>(p.pnb2, n0 + 1);
      stf_sc(p.x2T + n0 * 64 + lane,       fmaxf(xa, 0.f));
      stf_sc(p.x2T + (n0 + 1) * 64 + lane, fmaxf(xb, 0.f));
    }
    fastbar(p.flags, genp, ++bt, wg, tid);

    // ===== S3: gi0 | gh0 | gh1 — wg stages one 64KB k-part; waves share it =====
    {
      const float* src; const void* wb; float* dst;
      int n0, wstride, wc0;
      if (wg < 128) {               // gi0: kpart = wg&3, 32 n-groups
        int kpart = wg & 3, ngrp = wg >> 2;
        src = ((kpart < 2) ? p.x2T : p.attcT) + (kpart & 1) * 16384;
        wb = p.wih0; wstride = 1024;
        wc0 = (kpart >> 1) * 512 + (kpart & 1) * 256;
        n0 = (ngrp * 4 + wv) * 12;
        dst = p.gi0p + ((size_t)kpart * 1536 + n0) * 64;
      } else if (wg < 192) {        // gh0
        int idx = wg - 128, kpart = idx & 1, ngrp = idx >> 1;
        src = p.h0T + kpart * 16384;
        wb = p.whh0; wstride = 512; wc0 = kpart * 256;
        n0 = (ngrp * 4 + wv) * 12;
        dst = p.gh0p + ((size_t)kpart * 1536 + n0) * 64;
      } else {                      // gh1
        int idx = wg - 192, kpart = idx & 1, ngrp = idx >> 1;
        src = p.h1T + kpart * 16384;
        wb = p.whh1; wstride = 512; wc0 = kpart * 256;
        n0 = (ngrp * 4 + wv) * 12;
        dst = p.gh1p + ((size_t)kpart * 1536 + n0) * 64;
      }
      stage_n(stg, src, 16384, tid);
      __syncthreads();
      float acc[12];
#pragma unroll
      for (int i = 0; i < 12; ++i) acc[i] = 0.f;
      for (int kl = 0; kl < 256; ++kl) {
        float a = stg[kl * 64 + lane];
#pragma unroll
        for (int i = 0; i < 12; ++i)
          acc[i] = fmaf(ldw<F32>(wb, (size_t)(n0 + i) * wstride + wc0 + kl), a, acc[i]);
      }
#pragma unroll
      for (int i = 0; i < 12; ++i) stf_sc(dst + (size_t)i * 64 + lane, acc[i]);
    }
    fastbar(p.flags, genp, ++bt, wg, tid);

    // ===== S4: GRU0 combine -> h0' =====
    if (wg < 128) {
      int e = wg * 256 + tid;
      int h = e >> 6, b = e & 63;
      float ir = ldf_sc(p.gi0p + h * 64 + b) + ldf_sc(p.gi0p + (1536 + h) * 64 + b)
               + ldf_sc(p.gi0p + (3072 + h) * 64 + b) + ldf_sc(p.gi0p + (4608 + h) * 64 + b)
               + ldw<F32>(p.bih0, h);
      float iz = ldf_sc(p.gi0p + (512 + h) * 64 + b) + ldf_sc(p.gi0p + (2048 + h) * 64 + b)
               + ldf_sc(p.gi0p + (3584 + h) * 64 + b) + ldf_sc(p.gi0p + (5120 + h) * 64 + b)
               + ldw<F32>(p.bih0, 512 + h);
      float in = ldf_sc(p.gi0p + (1024 + h) * 64 + b) + ldf_sc(p.gi0p + (2560 + h) * 64 + b)
               + ldf_sc(p.gi0p + (4096 + h) * 64 + b) + ldf_sc(p.gi0p + (5632 + h) * 64 + b)
               + ldw<F32>(p.bih0, 1024 + h);
      float hr = ldf_sc(p.gh0p + h * 64 + b) + ldf_sc(p.gh0p + (1536 + h) * 64 + b)
               + ldw<F32>(p.bhh0, h);
      float hz = ldf_sc(p.gh0p + (512 + h) * 64 + b) + ldf_sc(p.gh0p + (2048 + h) * 64 + b)
               + ldw<F32>(p.bhh0, 512 + h);
      float hn = ldf_sc(p.gh0p + (1024 + h) * 64 + b) + ldf_sc(p.gh0p + (2560 + h) * 64 + b)
               + ldw<F32>(p.bhh0, 1024 + h);
      float r = sig_f(ir + hr), z = sig_f(iz + hz);
      float nn = tanh_f(in + r * hn);
      float ho = ldf_sc(p.h0T + h * 64 + b);
      stf_sc(p.h0T + h * 64 + b, (1.f - z) * nn + z * ho);
    }
    fastbar(p.flags, genp, ++bt, wg, tid);

    // ===== S5: gi1 | dec_next =====
    if (wg < 128) {                 // gi1: kpart = wg&3 (128-wide), 32 n-groups
      int kpart = wg & 3, ngrp = wg >> 2;
      stage_n(stg, p.h0T + kpart * 8192, 8192, tid);
      __syncthreads();
      int n0 = (ngrp * 4 + wv) * 12;
      float acc[12];
#pragma unroll
      for (int i = 0; i < 12; ++i) acc[i] = 0.f;
      for (int kl = 0; kl < 128; ++kl) {
        float a = stg[kl * 64 + lane];
#pragma unroll
        for (int i = 0; i < 12; ++i)
          acc[i] = fmaf(ldw<F32>(p.wih1, (size_t)(n0 + i) * 512 + kpart * 128 + kl), a, acc[i]);
      }
#pragma unroll
      for (int i = 0; i < 12; ++i)
        stf_sc(p.gi1p + ((size_t)kpart * 1536 + n0 + i) * 64 + lane, acc[i]);
    } else if (wg < 192) {          // dec: full h0T in two 64KB chunks
      int u = (wg - 128) * 4 + wv, n0 = u * 2;
      float r0 = 0.f, r1 = 0.f;
      for (int c = 0; c < 2; ++c) {
        stage_n(stg, p.h0T + c * 16384, 16384, tid);
        __syncthreads();
        int kb = c * 256;
        for (int kl = 0; kl < 256; ++kl) {
          float a = stg[kl * 64 + lane];
          r0 = fmaf(ldw<F32>(p.adec, (size_t)n0 * 512 + kb + kl),       a, r0);
          r1 = fmaf(ldw<F32>(p.adec, (size_t)(n0 + 1) * 512 + kb + kl), a, r1);
        }
        __syncthreads();
      }
      stf_sc(p.dec + lane * 512 + n0,     r0);
      stf_sc(p.dec + lane * 512 + n0 + 1, r1);
    }
    fastbar(p.flags, genp, ++bt, wg, tid);

    // ===== S6: GRU1 combine -> h1' =====
    if (wg < 128) {
      int e = wg * 256 + tid;
      int h = e >> 6, b = e & 63;
      float ir = ldf_sc(p.gi1p + h * 64 + b) + ldf_sc(p.gi1p + (1536 + h) * 64 + b)
               + ldf_sc(p.gi1p + (3072 + h) * 64 + b) + ldf_sc(p.gi1p + (4608 + h) * 64 + b)
               + ldw<F32>(p.bih1, h);
      float iz = ldf_sc(p.gi1p + (512 + h) * 64 + b) + ldf_sc(p.gi1p + (2048 + h) * 64 + b)
               + ldf_sc(p.gi1p + (3584 + h) * 64 + b) + ldf_sc(p.gi1p + (5120 + h) * 64 + b)
               + ldw<F32>(p.bih1, 512 + h);
      float in = ldf_sc(p.gi1p + (1024 + h) * 64 + b) + ldf_sc(p.gi1p + (2560 + h) * 64 + b)
               + ldf_sc(p.gi1p + (4096 + h) * 64 + b) + ldf_sc(p.gi1p + (5632 + h) * 64 + b)
               + ldw<F32>(p.bih1, 1024 + h);
      float hr = ldf_sc(p.gh1p + h * 64 + b) + ldf_sc(p.gh1p + (1536 + h) * 64 + b)
               + ldw<F32>(p.bhh1, h);
      float hz = ldf_sc(p.gh1p + (512 + h) * 64 + b) + ldf_sc(p.gh1p + (2048 + h) * 64 + b)
               + ldw<F32>(p.bhh1, 512 + h);
      float hn = ldf_sc(p.gh1p + (1024 + h) * 64 + b) + ldf_sc(p.gh1p + (2560 + h) * 64 + b)
               + ldw<F32>(p.bhh1, 1024 + h);
      float r = sig_f(ir + hr), z = sig_f(iz + hz);
      float nn = tanh_f(in + r * hn);
      float ho = ldf_sc(p.h1T + h * 64 + b);
      stf_sc(p.h1T + h * 64 + b, (1.f - z) * nn + z * ho);
    }
    fastbar(p.flags, genp, ++bt, wg, tid);

    // ===== S7: out = Wout @ [h1' ; att_c] + b — chunked LDS staging =====
    if (wg < 40) {
      int n = wg * 4 + wv;
      float ac0 = ldw<F32>(p.outb, n), ac1 = 0.f;
      for (int c = 0; c < 4; ++c) {
        const float* src = ((c < 2) ? p.h1T : p.attcT) + (c & 1) * 16384;
        stage_n(stg, src, 16384, tid);
        __syncthreads();
        size_t wr = (size_t)n * 1024 + c * 256;
        for (int kl = 0; kl < 256; kl += 2) {
          ac0 = fmaf(ldw<F32>(p.outw, wr + kl),     stg[kl * 64 + lane],       ac0);
          ac1 = fmaf(ldw<F32>(p.outw, wr + kl + 1), stg[(kl + 1) * 64 + lane], ac1);
        }
        __syncthreads();
      }
      float acc = ac0 + ac1;
      stf_sc(p.poT + n * 64 + lane, acc);
      stout<F32>(p.out, (size_t)lane * 81920 + (size_t)(n >> 1) * 1024 + t * 2 + (n & 1), acc);
    }
    fastbar(p.flags, genp, ++bt, wg, tid);
  }
}

// ---------------- host launcher ----------------
extern "C" void kernel_launch(void* const* d_in, const int* in_sizes, int n_in,
                              void* d_out, int out_size, void* d_ws, size_t ws_size,
                              hipStream_t stream) {
  (void)in_sizes; (void)n_in; (void)out_size; (void)ws_size;
  const void* enc   = d_in[0];
  const int*  dlen  = (const int*)d_in[1];
  const void* pnw1  = d_in[2];
  const void* pnb1  = d_in[3];
  const void* pnw2  = d_in[4];
  const void* pnb2  = d_in[5];
  const void* aencw = d_in[6];
  const void* aencb = d_in[7];
  const void* adecw = d_in[8];
  const void* aconv = d_in[9];
  const void* alocw = d_in[10];
  const void* avw   = d_in[11];
  // d_in[12] = att_v_b: softmax-invariant -> unused
  const void* wih0  = d_in[13];
  const void* whh0  = d_in[14];
  const void* bih0  = d_in[15];
  const void* bhh0  = d_in[16];
  const void* wih1  = d_in[17];
  const void* whh1  = d_in[18];
  const void* bih1  = d_in[19];
  const void* bhh1  = d_in[20];
  const void* outw  = d_in[21];
  const void* outb  = d_in[22];

  float* W = (float*)d_ws;
  int* flag = (int*)(W + OBAR) + 64;
  dim3 blk(256);

  k_zero<<<256, blk, 0, stream>>>(W + OBAR, ZERO_SPAN_N);
  k_detect<<<1, blk, 0, stream>>>(flag, (const u16*)pnw1);
  k_prevw<<<64, blk, 0, stream>>>(W + OPRV, dlen);
  // dual-dtype setup (wrong variant self-disables via flag)
  k_mmat<false><<<64, blk, 0, stream>>>(flag, W + OMM, alocw, aconv);
  k_mmat<true ><<<64, blk, 0, stream>>>(flag, W + OMM, alocw, aconv);
  k_cvtT512<false><<<512, blk, 0, stream>>>(flag, W + OGI0, aencw);
  k_cvtT512<true ><<<512, blk, 0, stream>>>(flag, W + OGI0, aencw);
  k_pm<false><<<2048, blk, 0, stream>>>(flag, (u16*)(W + OPM), enc, W + OGI0, aencb);
  k_pm<true ><<<2048, blk, 0, stream>>>(flag, (u16*)(W + OPM), enc, W + OGI0, aencb);

  KP kp;
  kp.enc = enc; kp.dlen = dlen;
  kp.pm = (const u16*)(W + OPM);
  kp.wih0 = wih0; kp.whh0 = whh0;
  kp.wih1 = wih1; kp.whh1 = whh1;
  kp.adec = adecw; kp.outw = outw;
  kp.pnw2 = pnw2; kp.pnw1 = pnw1;
  kp.pnb1 = pnb1; kp.pnb2 = pnb2;
  kp.bih0 = bih0; kp.bhh0 = bhh0;
  kp.bih1 = bih1; kp.bhh1 = bhh1;
  kp.outb = outb; kp.vw = avw;
  kp.Mg = W + OMM;
  kp.bar = (int*)(W + OBAR);
  kp.flags = (int*)(W + OFLG);
  kp.asum = W + OASUM; kp.dec = W + ODEC;
  kp.h0T = W + OH0; kp.h1T = W + OH1; kp.poT = W + OPO;
  kp.prevw = W + OPRV; kp.erg = W + OERG;
  kp.x1T = W + OX1; kp.x2T = W + OX2; kp.attcT = W + OATTC;
  kp.gi0p = W + OGI0; kp.gh0p = W + OGH0;
  kp.gh1p = W + OGH1; kp.gi1p = W + OGI1;
  kp.out = d_out;

  // both variants launched; the wrong-dtype one exits before touching the barrier
  k_loop<false><<<dim3(256), blk, 0, stream>>>(kp);
  k_loop<true ><<<dim3(256), blk, 0, stream>>>(kp);
}

// Round 3
// 117638.306 us; speedup vs baseline: 3.2986x; 1.0260x over previous
//
#include <hip/hip_runtime.h>
#include <hip/hip_bf16.h>

typedef unsigned short u16;

// ---------------- constants ----------------
// B=64, T=512, C=512, H=512, D=80, RF=2, PRE_IN=160, PRE_INNER=256, CONV_CH=32, K=31

__device__ __forceinline__ float b2f(u16 u) {
  return __uint_as_float(((unsigned)u) << 16);
}
__device__ __forceinline__ u16 f2b(float f) {   // RNE f32->bf16
  unsigned u = __float_as_uint(f);
  u += 0x7fffu + ((u >> 16) & 1u);
  return (u16)(u >> 16);
}
// dtype-generic input load / output store (F32: raw f32; else bf16 u16)
template<bool F32>
__device__ __forceinline__ float ldw(const void* p, size_t i) {
  return F32 ? ((const float*)p)[i] : b2f(((const u16*)p)[i]);
}
// 4 consecutive elements as float4 (16B or 8B single load)
template<bool F32>
__device__ __forceinline__ float4 ldw4(const void* p, size_t i) {
  if (F32) {
    return *(const float4*)((const float*)p + i);
  } else {
    uint2 u = *(const uint2*)((const u16*)p + i);
    float4 r;
    r.x = __uint_as_float(u.x << 16);
    r.y = __uint_as_float(u.x & 0xffff0000u);
    r.z = __uint_as_float(u.y << 16);
    r.w = __uint_as_float(u.y & 0xffff0000u);
    return r;
  }
}
template<bool F32>
__device__ __forceinline__ void stout(void* p, size_t i, float v) {
  if (F32) ((float*)p)[i] = v; else ((u16*)p)[i] = f2b(v);
}
__device__ __forceinline__ float frcp(float x) { return __builtin_amdgcn_rcpf(x); }
__device__ __forceinline__ float tanh_f(float x) {
  float e = __expf(2.f * x);
  return 1.f - 2.f * frcp(e + 1.f);     // inf-safe
}
__device__ __forceinline__ float sig_f(float x) { return frcp(1.f + __expf(-x)); }

// ---- relaxed agent-scope (MALL-coherent, fence-free) accessors ----
__device__ __forceinline__ void st_sc(int* p, int v) {
  __hip_atomic_store(p, v, __ATOMIC_RELAXED, __HIP_MEMORY_SCOPE_AGENT);
}
__device__ __forceinline__ int ld_sc(const int* p) {
  return __hip_atomic_load(p, __ATOMIC_RELAXED, __HIP_MEMORY_SCOPE_AGENT);
}
__device__ __forceinline__ void stf_sc(float* p, float v) {
  __hip_atomic_store(p, v, __ATOMIC_RELAXED, __HIP_MEMORY_SCOPE_AGENT);
}
__device__ __forceinline__ float ldf_sc(const float* p) {
  return __hip_atomic_load(p, __ATOMIC_RELAXED, __HIP_MEMORY_SCOPE_AGENT);
}

// Burst-copy n floats (n multiple of 2048) global->LDS with 16 (or 8) loads
// in flight per thread.
__device__ __forceinline__ void stage_n(float* lds, const float* src, int n, int tid) {
  int i = 0;
  for (; i + 4096 <= n; i += 4096) {
    float r[16];
#pragma unroll
    for (int j = 0; j < 16; ++j) r[j] = ldf_sc(src + i + tid + j * 256);
#pragma unroll
    for (int j = 0; j < 16; ++j) lds[i + tid + j * 256] = r[j];
  }
  for (; i < n; i += 2048) {
    float r[8];
#pragma unroll
    for (int j = 0; j < 8; ++j) r[j] = ldf_sc(src + i + tid + j * 256);
#pragma unroll
    for (int j = 0; j < 8; ++j) lds[i + tid + j * 256] = r[j];
  }
}

// ---- software-pipelined weight-streaming dot kernels ----
// Weights forced onto the VMEM path (vz = opaque VGPR zero) so their counted
// vmcnt waits are independent of the LDS (lgkm) activation reads; two-buffer
// prefetch hides L2 latency behind the FMA block.
template<bool F32>
__device__ __forceinline__ void dot12(float* __restrict__ acc, const float* __restrict__ sb,
                                      const void* __restrict__ wb, size_t rb, int wstride,
                                      int nk, int lane, int vz) {
  float4 wa[12], wn[12];
#pragma unroll
  for (int i = 0; i < 12; ++i) wa[i] = ldw4<F32>(wb, rb + (size_t)i * wstride + vz);
  for (int kg = 0; kg < nk; kg += 8) {
#pragma unroll
    for (int i = 0; i < 12; ++i) wn[i] = ldw4<F32>(wb, rb + (size_t)i * wstride + kg + 4 + vz);
    float a0 = sb[(kg + 0) * 64 + lane], a1 = sb[(kg + 1) * 64 + lane],
          a2 = sb[(kg + 2) * 64 + lane], a3 = sb[(kg + 3) * 64 + lane];
#pragma unroll
    for (int i = 0; i < 12; ++i)
      acc[i] = fmaf(wa[i].w, a3, fmaf(wa[i].z, a2, fmaf(wa[i].y, a1, fmaf(wa[i].x, a0, acc[i]))));
    int kn = (kg + 8 < nk) ? kg + 8 : kg;
#pragma unroll
    for (int i = 0; i < 12; ++i) wa[i] = ldw4<F32>(wb, rb + (size_t)i * wstride + kn + vz);
    float b0 = sb[(kg + 4) * 64 + lane], b1 = sb[(kg + 5) * 64 + lane],
          b2 = sb[(kg + 6) * 64 + lane], b3 = sb[(kg + 7) * 64 + lane];
#pragma unroll
    for (int i = 0; i < 12; ++i)
      acc[i] = fmaf(wn[i].w, b3, fmaf(wn[i].z, b2, fmaf(wn[i].y, b1, fmaf(wn[i].x, b0, acc[i]))));
  }
}
template<bool F32>
__device__ __forceinline__ void dot2(float& r0, float& r1, const float* __restrict__ sb,
                                     const void* __restrict__ wb, size_t rb0, size_t rb1,
                                     int nk, int lane, int vz) {
  float4 wa0 = ldw4<F32>(wb, rb0 + vz), wa1 = ldw4<F32>(wb, rb1 + vz);
  for (int kg = 0; kg < nk; kg += 8) {
    float4 wn0 = ldw4<F32>(wb, rb0 + kg + 4 + vz), wn1 = ldw4<F32>(wb, rb1 + kg + 4 + vz);
    float a0 = sb[(kg + 0) * 64 + lane], a1 = sb[(kg + 1) * 64 + lane],
          a2 = sb[(kg + 2) * 64 + lane], a3 = sb[(kg + 3) * 64 + lane];
    r0 = fmaf(wa0.w, a3, fmaf(wa0.z, a2, fmaf(wa0.y, a1, fmaf(wa0.x, a0, r0))));
    r1 = fmaf(wa1.w, a3, fmaf(wa1.z, a2, fmaf(wa1.y, a1, fmaf(wa1.x, a0, r1))));
    int kn = (kg + 8 < nk) ? kg + 8 : kg;
    wa0 = ldw4<F32>(wb, rb0 + kn + vz); wa1 = ldw4<F32>(wb, rb1 + kn + vz);
    float b0 = sb[(kg + 4) * 64 + lane], b1 = sb[(kg + 5) * 64 + lane],
          b2 = sb[(kg + 6) * 64 + lane], b3 = sb[(kg + 7) * 64 + lane];
    r0 = fmaf(wn0.w, b3, fmaf(wn0.z, b2, fmaf(wn0.y, b1, fmaf(wn0.x, b0, r0))));
    r1 = fmaf(wn1.w, b3, fmaf(wn1.z, b2, fmaf(wn1.y, b1, fmaf(wn1.x, b0, r1))));
  }
}
template<bool F32>
__device__ __forceinline__ void dot1(float& r0, const float* __restrict__ sb,
                                     const void* __restrict__ wb, size_t rb,
                                     int nk, int lane, int vz) {
  float4 wa = ldw4<F32>(wb, rb + vz);
  for (int kg = 0; kg < nk; kg += 8) {
    float4 wn = ldw4<F32>(wb, rb + kg + 4 + vz);
    float a0 = sb[(kg + 0) * 64 + lane], a1 = sb[(kg + 1) * 64 + lane],
          a2 = sb[(kg + 2) * 64 + lane], a3 = sb[(kg + 3) * 64 + lane];
    r0 = fmaf(wa.w, a3, fmaf(wa.z, a2, fmaf(wa.y, a1, fmaf(wa.x, a0, r0))));
    int kn = (kg + 8 < nk) ? kg + 8 : kg;
    wa = ldw4<F32>(wb, rb + kn + vz);
    float b0 = sb[(kg + 4) * 64 + lane], b1 = sb[(kg + 5) * 64 + lane],
          b2 = sb[(kg + 6) * 64 + lane], b3 = sb[(kg + 7) * 64 + lane];
    r0 = fmaf(wn.w, b3, fmaf(wn.z, b2, fmaf(wn.y, b1, fmaf(wn.x, b0, r0))));
  }
}

// ---------------- ws layout (float offsets), ~39.5 MB ----------------
constexpr size_t OBAR  = 0;                       // [32]=gen, [64]=dtype flag
constexpr size_t OFLG  = OBAR  + 128;             // per-wg arrival flags 256*32 ints
constexpr size_t OASUM = OFLG  + 8192;            // att_sum [b][t]     32768
constexpr size_t ODEC  = OASUM + 32768;           // dec    [b][h]      32768
constexpr size_t OH0   = ODEC  + 32768;           // h0T    [h][b]      32768
constexpr size_t OH1   = OH0   + 32768;           // h1T    [h][b]      32768
constexpr size_t OPO   = OH1   + 32768;           // poT    [n][b]      10240
constexpr size_t OZEND = OPO   + 10240;
constexpr int    ZERO_SPAN_N = (int)OZEND;
constexpr size_t OPRV  = OZEND;                   // prev_w [b][t]      32768
constexpr size_t OERG  = OPRV  + 32768;           // erg    [b][t]      32768
constexpr size_t OX1   = OERG  + 32768;           // x1T    [n][b]      16384
constexpr size_t OX2   = OX1   + 16384;           // x2T    [n][b]      32768
constexpr size_t OATTC = OX2   + 32768;           // attcT  [c][b]      32768
constexpr size_t OMM   = OATTC + 32768;           // M[h][32] f32       16384
constexpr size_t OGI0  = OMM   + 16384;           // gi0p [4][1536][64] 393216 (setup alias: encT)
constexpr size_t OGH0  = OGI0  + 393216;          // gh0p               196608
constexpr size_t OGH1  = OGH0  + 196608;          // gh1p               196608
constexpr size_t OGI1  = OGH1  + 196608;          // gi1p               393216
constexpr size_t OPM   = OGI1  + 393216;          // pm bf16 (16.7M u16 = 8388608 slots)
constexpr size_t OTOT  = OPM   + 8388608;

// ---------------- fence-free flag barrier ----------------
__device__ __forceinline__ void fastbar(int* flags, int* gen, int target,
                                        int wg, int tid) {
  __syncthreads();
  if (tid == 0) st_sc(flags + wg * 32, target);
  if (wg == 0) {
    if (tid < 64) {
      int i0 = tid * 4;
      for (;;) {
        int ok = (ld_sc(flags + (i0 + 0) * 32) >= target)
               & (ld_sc(flags + (i0 + 1) * 32) >= target)
               & (ld_sc(flags + (i0 + 2) * 32) >= target)
               & (ld_sc(flags + (i0 + 3) * 32) >= target);
        if (__ballot(ok) == 0xFFFFFFFFFFFFFFFFull) break;
      }
      if (tid == 0) st_sc(gen, target);
    }
    __syncthreads();
  } else {
    if (tid == 0) {
      while (ld_sc(gen) < target) {}
    }
    __syncthreads();
  }
}

// ---------------- setup kernels ----------------
__global__ void k_zero(float* p, int n) {
  for (int i = blockIdx.x * 256 + threadIdx.x; i < n; i += gridDim.x * 256) p[i] = 0.f;
}
__global__ void k_detect(int* flag, const u16* probe) {
  if (blockIdx.x != 0 || threadIdx.x != 0) return;
  int sane = 0;
  for (int i = 0; i < 256; i += 2) {
    u16 u = probe[i];
    int e = (u >> 7) & 0xFF;
    if (u == 0 || (e >= 97 && e <= 140)) ++sane;
  }
  *flag = (sane < 96) ? 1 : 0;   // 1 => inputs are raw f32
}
__global__ void k_prevw(float* prevw, const int* dlen) {
  int b = blockIdx.x;
  int len = dlen[b] >> 1;
  float inv = 1.f / (float)len;
  for (int i = threadIdx.x; i < 512; i += 256)
    prevw[b * 512 + i] = (i < len) ? inv : 0.f;
}
template<bool F32>
__global__ void k_cvtT512(const int* flag, float* dst, const void* src) {
  if (*flag != (F32 ? 1 : 0)) return;
  for (int i = blockIdx.x * 256 + threadIdx.x; i < 262144; i += gridDim.x * 256) {
    int c = i >> 9, h = i & 511;
    dst[i] = ldw<F32>(src, (size_t)h * 512 + c);
  }
}
template<bool F32>
__global__ void k_mmat(const int* flag, float* M, const void* locw, const void* convw) {
  if (*flag != (F32 ? 1 : 0)) return;
  int i = blockIdx.x * 256 + threadIdx.x;
  if (i >= 16384) return;
  int h = i >> 5, k = i & 31;
  float acc = 0.f;
  if (k < 31) {
    for (int c = 0; c < 32; ++c)
      acc = fmaf(ldw<F32>(locw, h * 32 + c), ldw<F32>(convw, c * 31 + k), acc);
  }
  M[i] = acc;
}
template<bool F32>
__global__ __launch_bounds__(256) void k_pm(const int* flag, u16* pm, const void* enc,
                                            const float* encwT, const void* encb) {
  if (*flag != (F32 ? 1 : 0)) return;
  __shared__ float encf[16 * 512];
  int row0 = blockIdx.x * 16;
  int tid = threadIdx.x;
  for (int i = tid; i < 16 * 512; i += 256) {
    int r = i >> 9, c = i & 511;
    encf[i] = ldw<F32>(enc, (size_t)(row0 + r) * 512 + c);
  }
  __syncthreads();
  float a0[16], a1[16];
  float bb0 = ldw<F32>(encb, tid), bb1 = ldw<F32>(encb, tid + 256);
#pragma unroll
  for (int r = 0; r < 16; ++r) { a0[r] = bb0; a1[r] = bb1; }
  for (int c = 0; c < 512; ++c) {
    float w0 = encwT[c * 512 + tid];
    float w1 = encwT[c * 512 + 256 + tid];
#pragma unroll
    for (int r = 0; r < 16; ++r) {
      float a = encf[r * 512 + c];
      a0[r] = fmaf(w0, a, a0[r]);
      a1[r] = fmaf(w1, a, a1[r]);
    }
  }
#pragma unroll
  for (int r = 0; r < 16; ++r) {
    pm[(size_t)(row0 + r) * 512 + tid]       = f2b(a0[r]);
    pm[(size_t)(row0 + r) * 512 + 256 + tid] = f2b(a1[r]);
  }
}

// ---------------- main persistent kernel ----------------
struct KP {
  const void* __restrict__ enc;
  const int* __restrict__ dlen;
  const u16* __restrict__ pm;          // internal bf16
  const void* __restrict__ wih0; const void* __restrict__ whh0;
  const void* __restrict__ wih1; const void* __restrict__ whh1;
  const void* __restrict__ adec; const void* __restrict__ outw;
  const void* __restrict__ pnw2; const void* __restrict__ pnw1;
  const void* __restrict__ pnb1; const void* __restrict__ pnb2;
  const void* __restrict__ bih0; const void* __restrict__ bhh0;
  const void* __restrict__ bih1; const void* __restrict__ bhh1;
  const void* __restrict__ outb; const void* __restrict__ vw;
  const float* __restrict__ Mg;
  int* __restrict__ bar;               // [32]=gen, [64]=dtype
  int* __restrict__ flags;             // 256 * 32 ints
  float* __restrict__ asum; float* __restrict__ dec;
  float* __restrict__ h0T;  float* __restrict__ h1T;  float* __restrict__ poT;
  float* __restrict__ prevw; float* __restrict__ erg;
  float* __restrict__ x1T;  float* __restrict__ x2T;  float* __restrict__ attcT;
  float* __restrict__ gi0p; float* __restrict__ gh0p;
  float* __restrict__ gh1p; float* __restrict__ gi1p;
  void* __restrict__ out;              // out_o at elem 0; out_a at elem 5242880
};

template<bool F32>
__global__ __launch_bounds__(256, 1) void k_loop(KP p) {
  if (*(const volatile int*)(p.bar + 64) != (F32 ? 1 : 0)) return;  // wrong-dtype variant exits
  __shared__ float stg[16384];       // 64 KB activation staging buffer
  __shared__ u16  M_u[32 * 512];
  __shared__ float dec_s[512];
  __shared__ float v_s[512];
  __shared__ float wq[160];
  __shared__ float sm[512];
  __shared__ float red[8];

  const int wg = blockIdx.x, tid = threadIdx.x;
  const int lane = tid & 63;
  const int wv = __builtin_amdgcn_readfirstlane(tid >> 6);
  const int wflat = wg * 4 + wv;
  const int b_att = wg >> 2, q = wg & 3, t0 = q * 128;
  const int trow = tid >> 6, hcol = tid & 63;
  int* genp = p.bar + 32;
  int bt = 0;
  int vz;                            // opaque VGPR zero: forces VMEM path for weights
  asm volatile("v_mov_b32 %0, 0" : "=v"(vz));

  for (int i = tid; i < 32 * 512; i += 256) {
    int k = i >> 9, h = i & 511;
    M_u[i] = f2b(p.Mg[h * 32 + k]);
  }
  for (int i = tid; i < 512; i += 256) v_s[i] = ldw<F32>(p.vw, i);
  __syncthreads();

  for (int t = 0; t < 512; ++t) {
    // ===== S1: attention energies (+ prenet-1 from LDS-staged poT) =====
    if (wg < 64) stage_n(stg, p.poT, 10240, tid);   // poT [160][64] shared by 4 waves
    if (tid < 158) {
      int g = t0 - 15 + tid;
      wq[tid] = (g >= 0 && g < 512) ? ldf_sc(p.prevw + b_att * 512 + g) : 0.f;
    }
    for (int i = tid; i < 512; i += 256) dec_s[i] = ldf_sc(p.dec + b_att * 512 + i);
    __syncthreads();
    if (wg < 64) {
      int n = wg * 4 + wv;
      float a = 0.f;
      dot1<F32>(a, stg, p.pnw1, (size_t)n * 160, 160, lane, vz);
      a += ldw<F32>(p.pnb1, n);
      stf_sc(p.x1T + n * 64 + lane, fmaxf(a, 0.f));
    }
    {
      float wreg[62];
#pragma unroll
      for (int i = 0; i < 62; ++i) wreg[i] = wq[trow * 32 + i];
      float acc[32];
#pragma unroll
      for (int s = 0; s < 32; ++s) acc[s] = 0.f;
      const u16* pmb = p.pm + ((size_t)(b_att * 512 + t0 + trow * 32)) * 512;
      for (int j = 0; j < 8; ++j) {
        int hj = hcol + 64 * j;
        float Mreg[31];
#pragma unroll
        for (int k = 0; k < 31; ++k) Mreg[k] = b2f(M_u[k * 512 + hj]);
        float dj = dec_s[hj], vj = v_s[hj];
#pragma unroll
        for (int s = 0; s < 32; ++s) {
          float u = dj;
#pragma unroll
          for (int k = 0; k < 31; ++k) u = fmaf(Mreg[k], wreg[s + k], u);
          u += b2f(pmb[s * 512 + hj]);
          acc[s] = fmaf(vj, tanh_f(u), acc[s]);
        }
      }
#pragma unroll
      for (int s = 0; s < 32; ++s) {
        float v = acc[s];
#pragma unroll
        for (int off = 32; off; off >>= 1) v += __shfl_xor(v, off, 64);
        if (hcol == 0) sm[trow * 32 + s] = v;
      }
      __syncthreads();
      if (tid < 128) stf_sc(p.erg + b_att * 512 + t0 + tid, sm[tid]);
    }
    fastbar(p.flags, genp, ++bt, wg, tid);

    // ===== S2: softmax/out_a | att_c | prenet-2 =====
    if (wg < 64) {
      int b = wg;
      int len = p.dlen[b] >> 1;
      float e0 = ldf_sc(p.erg + b * 512 + tid), e1 = ldf_sc(p.erg + b * 512 + 256 + tid);
      bool v0 = tid < len, v1 = (256 + tid) < len;
      float mx = fmaxf(v0 ? e0 : -1e30f, v1 ? e1 : -1e30f);
#pragma unroll
      for (int off = 32; off; off >>= 1) mx = fmaxf(mx, __shfl_xor(mx, off, 64));
      if (lane == 0) red[wv] = mx;
      __syncthreads();
      mx = fmaxf(fmaxf(red[0], red[1]), fmaxf(red[2], red[3]));
      float x0 = v0 ? __expf(e0 - mx) : 0.f;
      float x1 = v1 ? __expf(e1 - mx) : 0.f;
      float s = x0 + x1;
#pragma unroll
      for (int off = 32; off; off >>= 1) s += __shfl_xor(s, off, 64);
      if (lane == 0) red[4 + wv] = s;
      __syncthreads();
      s = red[4] + red[5] + red[6] + red[7];
      float inv = 1.f / s;
      float w0 = x0 * inv, w1 = x1 * inv;
      stout<F32>(p.out, 5242880 + (size_t)b * 262144 + (size_t)tid * 512 + t, w0);
      stout<F32>(p.out, 5242880 + (size_t)b * 262144 + (size_t)(tid + 256) * 512 + t, w1);
      float s0 = p.asum[b * 512 + tid] + w0;
      float s1 = p.asum[b * 512 + 256 + tid] + w1;
      p.asum[b * 512 + tid] = s0;          stf_sc(p.prevw + b * 512 + tid, s0);
      p.asum[b * 512 + 256 + tid] = s1;    stf_sc(p.prevw + b * 512 + 256 + tid, s1);
    } else if (wg < 192) {
      int idx = wg - 64, b = idx >> 1, half = idx & 1;
      int len = p.dlen[b] >> 1;
      float e0 = ldf_sc(p.erg + b * 512 + tid), e1 = ldf_sc(p.erg + b * 512 + 256 + tid);
      bool v0 = tid < len, v1 = (256 + tid) < len;
      float mx = fmaxf(v0 ? e0 : -1e30f, v1 ? e1 : -1e30f);
#pragma unroll
      for (int off = 32; off; off >>= 1) mx = fmaxf(mx, __shfl_xor(mx, off, 64));
      if (lane == 0) red[wv] = mx;
      __syncthreads();
      mx = fmaxf(fmaxf(red[0], red[1]), fmaxf(red[2], red[3]));
      float x0 = v0 ? __expf(e0 - mx) : 0.f;
      float x1 = v1 ? __expf(e1 - mx) : 0.f;
      float s = x0 + x1;
#pragma unroll
      for (int off = 32; off; off >>= 1) s += __shfl_xor(s, off, 64);
      if (lane == 0) red[4 + wv] = s;
      __syncthreads();
      s = red[4] + red[5] + red[6] + red[7];
      float inv = 1.f / s;
      sm[tid] = x0 * inv; sm[256 + tid] = x1 * inv;
      __syncthreads();
      int c = half * 256 + tid;
      size_t eb = (size_t)b * 262144 + c;
      float aa[16];
#pragma unroll
      for (int i = 0; i < 16; ++i) aa[i] = 0.f;
      for (int tau = 0; tau < 512; tau += 16) {
#pragma unroll
        for (int i = 0; i < 16; ++i)
          aa[i] = fmaf(sm[tau + i], ldw<F32>(p.enc, eb + (size_t)(tau + i) * 512), aa[i]);
      }
      float r = 0.f;
#pragma unroll
      for (int i = 0; i < 16; ++i) r += aa[i];
      stf_sc(p.attcT + c * 64 + b, r);
    } else {
      stage_n(stg, p.x1T, 16384, tid);           // x1T [256][64] shared by 4 waves
      __syncthreads();
      int idx = wg - 192;
      int n0 = (idx * 4 + wv) * 2;
      float xa = 0.f, xb = 0.f;
      dot2<F32>(xa, xb, stg, p.pnw2, (size_t)n0 * 256, (size_t)(n0 + 1) * 256, 256, lane, vz);
      xa += ldw<F32>(p.pnb2, n0); xb += ldw<F32>(p.pnb2, n0 + 1);
      stf_sc(p.x2T + n0 * 64 + lane,       fmaxf(xa, 0.f));
      stf_sc(p.x2T + (n0 + 1) * 64 + lane, fmaxf(xb, 0.f));
    }
    fastbar(p.flags, genp, ++bt, wg, tid);

    // ===== S3: gi0 | gh0 | gh1 — wg stages one 64KB k-part; waves share it =====
    {
      const float* src; const void* wb; float* dst;
      int n0, wstride, wc0;
      if (wg < 128) {               // gi0: kpart = wg&3, 32 n-groups
        int kpart = wg & 3, ngrp = wg >> 2;
        src = ((kpart < 2) ? p.x2T : p.attcT) + (kpart & 1) * 16384;
        wb = p.wih0; wstride = 1024;
        wc0 = (kpart >> 1) * 512 + (kpart & 1) * 256;
        n0 = (ngrp * 4 + wv) * 12;
        dst = p.gi0p + ((size_t)kpart * 1536 + n0) * 64;
      } else if (wg < 192) {        // gh0
        int idx = wg - 128, kpart = idx & 1, ngrp = idx >> 1;
        src = p.h0T + kpart * 16384;
        wb = p.whh0; wstride = 512; wc0 = kpart * 256;
        n0 = (ngrp * 4 + wv) * 12;
        dst = p.gh0p + ((size_t)kpart * 1536 + n0) * 64;
      } else {                      // gh1
        int idx = wg - 192, kpart = idx & 1, ngrp = idx >> 1;
        src = p.h1T + kpart * 16384;
        wb = p.whh1; wstride = 512; wc0 = kpart * 256;
        n0 = (ngrp * 4 + wv) * 12;
        dst = p.gh1p + ((size_t)kpart * 1536 + n0) * 64;
      }
      stage_n(stg, src, 16384, tid);
      __syncthreads();
      float acc[12];
#pragma unroll
      for (int i = 0; i < 12; ++i) acc[i] = 0.f;
      dot12<F32>(acc, stg, wb, (size_t)n0 * wstride + wc0, wstride, 256, lane, vz);
#pragma unroll
      for (int i = 0; i < 12; ++i) stf_sc(dst + (size_t)i * 64 + lane, acc[i]);
    }
    fastbar(p.flags, genp, ++bt, wg, tid);

    // ===== S4: GRU0 combine -> h0' =====
    if (wg < 128) {
      int e = wg * 256 + tid;
      int h = e >> 6, b = e & 63;
      float ir = ldf_sc(p.gi0p + h * 64 + b) + ldf_sc(p.gi0p + (1536 + h) * 64 + b)
               + ldf_sc(p.gi0p + (3072 + h) * 64 + b) + ldf_sc(p.gi0p + (4608 + h) * 64 + b)
               + ldw<F32>(p.bih0, h);
      float iz = ldf_sc(p.gi0p + (512 + h) * 64 + b) + ldf_sc(p.gi0p + (2048 + h) * 64 + b)
               + ldf_sc(p.gi0p + (3584 + h) * 64 + b) + ldf_sc(p.gi0p + (5120 + h) * 64 + b)
               + ldw<F32>(p.bih0, 512 + h);
      float in = ldf_sc(p.gi0p + (1024 + h) * 64 + b) + ldf_sc(p.gi0p + (2560 + h) * 64 + b)
               + ldf_sc(p.gi0p + (4096 + h) * 64 + b) + ldf_sc(p.gi0p + (5632 + h) * 64 + b)
               + ldw<F32>(p.bih0, 1024 + h);
      float hr = ldf_sc(p.gh0p + h * 64 + b) + ldf_sc(p.gh0p + (1536 + h) * 64 + b)
               + ldw<F32>(p.bhh0, h);
      float hz = ldf_sc(p.gh0p + (512 + h) * 64 + b) + ldf_sc(p.gh0p + (2048 + h) * 64 + b)
               + ldw<F32>(p.bhh0, 512 + h);
      float hn = ldf_sc(p.gh0p + (1024 + h) * 64 + b) + ldf_sc(p.gh0p + (2560 + h) * 64 + b)
               + ldw<F32>(p.bhh0, 1024 + h);
      float r = sig_f(ir + hr), z = sig_f(iz + hz);
      float nn = tanh_f(in + r * hn);
      float ho = ldf_sc(p.h0T + h * 64 + b);
      stf_sc(p.h0T + h * 64 + b, (1.f - z) * nn + z * ho);
    }
    fastbar(p.flags, genp, ++bt, wg, tid);

    // ===== S5: gi1 | dec_next =====
    if (wg < 128) {                 // gi1: kpart = wg&3 (128-wide), 32 n-groups
      int kpart = wg & 3, ngrp = wg >> 2;
      stage_n(stg, p.h0T + kpart * 8192, 8192, tid);
      __syncthreads();
      int n0 = (ngrp * 4 + wv) * 12;
      float acc[12];
#pragma unroll
      for (int i = 0; i < 12; ++i) acc[i] = 0.f;
      dot12<F32>(acc, stg, p.wih1, (size_t)n0 * 512 + kpart * 128, 512, 128, lane, vz);
#pragma unroll
      for (int i = 0; i < 12; ++i)
        stf_sc(p.gi1p + ((size_t)kpart * 1536 + n0 + i) * 64 + lane, acc[i]);
    } else if (wg < 192) {          // dec: full h0T in two 64KB chunks
      int u = (wg - 128) * 4 + wv, n0 = u * 2;
      float r0 = 0.f, r1 = 0.f;
      for (int c = 0; c < 2; ++c) {
        stage_n(stg, p.h0T + c * 16384, 16384, tid);
        __syncthreads();
        dot2<F32>(r0, r1, stg, p.adec, (size_t)n0 * 512 + c * 256,
                  (size_t)(n0 + 1) * 512 + c * 256, 256, lane, vz);
        __syncthreads();
      }
      stf_sc(p.dec + lane * 512 + n0,     r0);
      stf_sc(p.dec + lane * 512 + n0 + 1, r1);
    }
    fastbar(p.flags, genp, ++bt, wg, tid);

    // ===== S6: GRU1 combine -> h1' =====
    if (wg < 128) {
      int e = wg * 256 + tid;
      int h = e >> 6, b = e & 63;
      float ir = ldf_sc(p.gi1p + h * 64 + b) + ldf_sc(p.gi1p + (1536 + h) * 64 + b)
               + ldf_sc(p.gi1p + (3072 + h) * 64 + b) + ldf_sc(p.gi1p + (4608 + h) * 64 + b)
               + ldw<F32>(p.bih1, h);
      float iz = ldf_sc(p.gi1p + (512 + h) * 64 + b) + ldf_sc(p.gi1p + (2048 + h) * 64 + b)
               + ldf_sc(p.gi1p + (3584 + h) * 64 + b) + ldf_sc(p.gi1p + (5120 + h) * 64 + b)
               + ldw<F32>(p.bih1, 512 + h);
      float in = ldf_sc(p.gi1p + (1024 + h) * 64 + b) + ldf_sc(p.gi1p + (2560 + h) * 64 + b)
               + ldf_sc(p.gi1p + (4096 + h) * 64 + b) + ldf_sc(p.gi1p + (5632 + h) * 64 + b)
               + ldw<F32>(p.bih1, 1024 + h);
      float hr = ldf_sc(p.gh1p + h * 64 + b) + ldf_sc(p.gh1p + (1536 + h) * 64 + b)
               + ldw<F32>(p.bhh1, h);
      float hz = ldf_sc(p.gh1p + (512 + h) * 64 + b) + ldf_sc(p.gh1p + (2048 + h) * 64 + b)
               + ldw<F32>(p.bhh1, 512 + h);
      float hn = ldf_sc(p.gh1p + (1024 + h) * 64 + b) + ldf_sc(p.gh1p + (2560 + h) * 64 + b)
               + ldw<F32>(p.bhh1, 1024 + h);
      float r = sig_f(ir + hr), z = sig_f(iz + hz);
      float nn = tanh_f(in + r * hn);
      float ho = ldf_sc(p.h1T + h * 64 + b);
      stf_sc(p.h1T + h * 64 + b, (1.f - z) * nn + z * ho);
    }
    fastbar(p.flags, genp, ++bt, wg, tid);

    // ===== S7: out = Wout @ [h1' ; att_c] + b — chunked LDS staging =====
    if (wg < 40) {
      int n = wg * 4 + wv;
      float r = 0.f;
      for (int c = 0; c < 4; ++c) {
        const float* src = ((c < 2) ? p.h1T : p.attcT) + (c & 1) * 16384;
        stage_n(stg, src, 16384, tid);
        __syncthreads();
        dot1<F32>(r, stg, p.outw, (size_t)n * 1024 + c * 256, 256, lane, vz);
        __syncthreads();
      }
      float acc = r + ldw<F32>(p.outb, n);
      stf_sc(p.poT + n * 64 + lane, acc);
      stout<F32>(p.out, (size_t)lane * 81920 + (size_t)(n >> 1) * 1024 + t * 2 + (n & 1), acc);
    }
    fastbar(p.flags, genp, ++bt, wg, tid);
  }
}

// ---------------- host launcher ----------------
extern "C" void kernel_launch(void* const* d_in, const int* in_sizes, int n_in,
                              void* d_out, int out_size, void* d_ws, size_t ws_size,
                              hipStream_t stream) {
  (void)in_sizes; (void)n_in; (void)out_size; (void)ws_size;
  const void* enc   = d_in[0];
  const int*  dlen  = (const int*)d_in[1];
  const void* pnw1  = d_in[2];
  const void* pnb1  = d_in[3];
  const void* pnw2  = d_in[4];
  const void* pnb2  = d_in[5];
  const void* aencw = d_in[6];
  const void* aencb = d_in[7];
  const void* adecw = d_in[8];
  const void* aconv = d_in[9];
  const void* alocw = d_in[10];
  const void* avw   = d_in[11];
  // d_in[12] = att_v_b: softmax-invariant -> unused
  const void* wih0  = d_in[13];
  const void* whh0  = d_in[14];
  const void* bih0  = d_in[15];
  const void* bhh0  = d_in[16];
  const void* wih1  = d_in[17];
  const void* whh1  = d_in[18];
  const void* bih1  = d_in[19];
  const void* bhh1  = d_in[20];
  const void* outw  = d_in[21];
  const void* outb  = d_in[22];

  float* W = (float*)d_ws;
  int* flag = (int*)(W + OBAR) + 64;
  dim3 blk(256);

  k_zero<<<256, blk, 0, stream>>>(W + OBAR, ZERO_SPAN_N);
  k_detect<<<1, blk, 0, stream>>>(flag, (const u16*)pnw1);
  k_prevw<<<64, blk, 0, stream>>>(W + OPRV, dlen);
  // dual-dtype setup (wrong variant self-disables via flag)
  k_mmat<false><<<64, blk, 0, stream>>>(flag, W + OMM, alocw, aconv);
  k_mmat<true ><<<64, blk, 0, stream>>>(flag, W + OMM, alocw, aconv);
  k_cvtT512<false><<<512, blk, 0, stream>>>(flag, W + OGI0, aencw);
  k_cvtT512<true ><<<512, blk, 0, stream>>>(flag, W + OGI0, aencw);
  k_pm<false><<<2048, blk, 0, stream>>>(flag, (u16*)(W + OPM), enc, W + OGI0, aencb);
  k_pm<true ><<<2048, blk, 0, stream>>>(flag, (u16*)(W + OPM), enc, W + OGI0, aencb);

  KP kp;
  kp.enc = enc; kp.dlen = dlen;
  kp.pm = (const u16*)(W + OPM);
  kp.wih0 = wih0; kp.whh0 = whh0;
  kp.wih1 = wih1; kp.whh1 = whh1;
  kp.adec = adecw; kp.outw = outw;
  kp.pnw2 = pnw2; kp.pnw1 = pnw1;
  kp.pnb1 = pnb1; kp.pnb2 = pnb2;
  kp.bih0 = bih0; kp.bhh0 = bhh0;
  kp.bih1 = bih1; kp.bhh1 = bhh1;
  kp.outb = outb; kp.vw = avw;
  kp.Mg = W + OMM;
  kp.bar = (int*)(W + OBAR);
  kp.flags = (int*)(W + OFLG);
  kp.asum = W + OASUM; kp.dec = W + ODEC;
  kp.h0T = W + OH0; kp.h1T = W + OH1; kp.poT = W + OPO;
  kp.prevw = W + OPRV; kp.erg = W + OERG;
  kp.x1T = W + OX1; kp.x2T = W + OX2; kp.attcT = W + OATTC;
  kp.gi0p = W + OGI0; kp.gh0p = W + OGH0;
  kp.gh1p = W + OGH1; kp.gi1p = W + OGI1;
  kp.out = d_out;

  // both variants launched; the wrong-dtype one exits before touching the barrier
  k_loop<false><<<dim3(256), blk, 0, stream>>>(kp);
  k_loop<true ><<<dim3(256), blk, 0, stream>>>(kp);
}

// Round 4
// 110210.535 us; speedup vs baseline: 3.5210x; 1.0674x over previous
//
#include <hip/hip_runtime.h>
#include <hip/hip_bf16.h>

typedef unsigned short u16;

// ---------------- constants ----------------
// B=64, T=512, C=512, H=512, D=80, RF=2, PRE_IN=160, PRE_INNER=256, CONV_CH=32, K=31

__device__ __forceinline__ float b2f(u16 u) {
  return __uint_as_float(((unsigned)u) << 16);
}
__device__ __forceinline__ u16 f2b(float f) {   // RNE f32->bf16
  unsigned u = __float_as_uint(f);
  u += 0x7fffu + ((u >> 16) & 1u);
  return (u16)(u >> 16);
}
// dtype-generic input load / output store (F32: raw f32; else bf16 u16)
template<bool F32>
__device__ __forceinline__ float ldw(const void* p, size_t i) {
  return F32 ? ((const float*)p)[i] : b2f(((const u16*)p)[i]);
}
// 4 consecutive elements as float4 (16B or 8B single load)
template<bool F32>
__device__ __forceinline__ float4 ldw4(const void* p, size_t i) {
  if (F32) {
    return *(const float4*)((const float*)p + i);
  } else {
    uint2 u = *(const uint2*)((const u16*)p + i);
    float4 r;
    r.x = __uint_as_float(u.x << 16);
    r.y = __uint_as_float(u.x & 0xffff0000u);
    r.z = __uint_as_float(u.y << 16);
    r.w = __uint_as_float(u.y & 0xffff0000u);
    return r;
  }
}
template<bool F32>
__device__ __forceinline__ void stout(void* p, size_t i, float v) {
  if (F32) ((float*)p)[i] = v; else ((u16*)p)[i] = f2b(v);
}
__device__ __forceinline__ float frcp(float x) { return __builtin_amdgcn_rcpf(x); }
__device__ __forceinline__ float tanh_f(float x) {
  float e = __expf(2.f * x);
  return 1.f - 2.f * frcp(e + 1.f);     // inf-safe
}
__device__ __forceinline__ float sig_f(float x) { return frcp(1.f + __expf(-x)); }

// ---- relaxed agent-scope (MALL-coherent, fence-free) accessors ----
__device__ __forceinline__ void st_sc(int* p, int v) {
  __hip_atomic_store(p, v, __ATOMIC_RELAXED, __HIP_MEMORY_SCOPE_AGENT);
}
__device__ __forceinline__ int ld_sc(const int* p) {
  return __hip_atomic_load(p, __ATOMIC_RELAXED, __HIP_MEMORY_SCOPE_AGENT);
}
__device__ __forceinline__ void stf_sc(float* p, float v) {
  __hip_atomic_store(p, v, __ATOMIC_RELAXED, __HIP_MEMORY_SCOPE_AGENT);
}
__device__ __forceinline__ float ldf_sc(const float* p) {
  return __hip_atomic_load(p, __ATOMIC_RELAXED, __HIP_MEMORY_SCOPE_AGENT);
}

// Burst-copy n floats (n multiple of 2048) global->LDS with 16 (or 8) loads
// in flight per thread.
__device__ __forceinline__ void stage_n(float* lds, const float* src, int n, int tid) {
  int i = 0;
  for (; i + 4096 <= n; i += 4096) {
    float r[16];
#pragma unroll
    for (int j = 0; j < 16; ++j) r[j] = ldf_sc(src + i + tid + j * 256);
#pragma unroll
    for (int j = 0; j < 16; ++j) lds[i + tid + j * 256] = r[j];
  }
  for (; i < n; i += 2048) {
    float r[8];
#pragma unroll
    for (int j = 0; j < 8; ++j) r[j] = ldf_sc(src + i + tid + j * 256);
#pragma unroll
    for (int j = 0; j < 8; ++j) lds[i + tid + j * 256] = r[j];
  }
}

// ---- software-pipelined weight-streaming dot kernels ----
template<bool F32>
__device__ __forceinline__ void dot12(float* __restrict__ acc, const float* __restrict__ sb,
                                      const void* __restrict__ wb, size_t rb, int wstride,
                                      int nk, int lane, int vz) {
  float4 wa[12], wn[12];
#pragma unroll
  for (int i = 0; i < 12; ++i) wa[i] = ldw4<F32>(wb, rb + (size_t)i * wstride + vz);
  for (int kg = 0; kg < nk; kg += 8) {
#pragma unroll
    for (int i = 0; i < 12; ++i) wn[i] = ldw4<F32>(wb, rb + (size_t)i * wstride + kg + 4 + vz);
    float a0 = sb[(kg + 0) * 64 + lane], a1 = sb[(kg + 1) * 64 + lane],
          a2 = sb[(kg + 2) * 64 + lane], a3 = sb[(kg + 3) * 64 + lane];
#pragma unroll
    for (int i = 0; i < 12; ++i)
      acc[i] = fmaf(wa[i].w, a3, fmaf(wa[i].z, a2, fmaf(wa[i].y, a1, fmaf(wa[i].x, a0, acc[i]))));
    int kn = (kg + 8 < nk) ? kg + 8 : kg;
#pragma unroll
    for (int i = 0; i < 12; ++i) wa[i] = ldw4<F32>(wb, rb + (size_t)i * wstride + kn + vz);
    float b0 = sb[(kg + 4) * 64 + lane], b1 = sb[(kg + 5) * 64 + lane],
          b2 = sb[(kg + 6) * 64 + lane], b3 = sb[(kg + 7) * 64 + lane];
#pragma unroll
    for (int i = 0; i < 12; ++i)
      acc[i] = fmaf(wn[i].w, b3, fmaf(wn[i].z, b2, fmaf(wn[i].y, b1, fmaf(wn[i].x, b0, acc[i]))));
  }
}
template<bool F32>
__device__ __forceinline__ void dot2(float& r0, float& r1, const float* __restrict__ sb,
                                     const void* __restrict__ wb, size_t rb0, size_t rb1,
                                     int nk, int lane, int vz) {
  float4 wa0 = ldw4<F32>(wb, rb0 + vz), wa1 = ldw4<F32>(wb, rb1 + vz);
  for (int kg = 0; kg < nk; kg += 8) {
    float4 wn0 = ldw4<F32>(wb, rb0 + kg + 4 + vz), wn1 = ldw4<F32>(wb, rb1 + kg + 4 + vz);
    float a0 = sb[(kg + 0) * 64 + lane], a1 = sb[(kg + 1) * 64 + lane],
          a2 = sb[(kg + 2) * 64 + lane], a3 = sb[(kg + 3) * 64 + lane];
    r0 = fmaf(wa0.w, a3, fmaf(wa0.z, a2, fmaf(wa0.y, a1, fmaf(wa0.x, a0, r0))));
    r1 = fmaf(wa1.w, a3, fmaf(wa1.z, a2, fmaf(wa1.y, a1, fmaf(wa1.x, a0, r1))));
    int kn = (kg + 8 < nk) ? kg + 8 : kg;
    wa0 = ldw4<F32>(wb, rb0 + kn + vz); wa1 = ldw4<F32>(wb, rb1 + kn + vz);
    float b0 = sb[(kg + 4) * 64 + lane], b1 = sb[(kg + 5) * 64 + lane],
          b2 = sb[(kg + 6) * 64 + lane], b3 = sb[(kg + 7) * 64 + lane];
    r0 = fmaf(wn0.w, b3, fmaf(wn0.z, b2, fmaf(wn0.y, b1, fmaf(wn0.x, b0, r0))));
    r1 = fmaf(wn1.w, b3, fmaf(wn1.z, b2, fmaf(wn1.y, b1, fmaf(wn1.x, b0, r1))));
  }
}
template<bool F32>
__device__ __forceinline__ void dot1(float& r0, const float* __restrict__ sb,
                                     const void* __restrict__ wb, size_t rb,
                                     int nk, int lane, int vz) {
  float4 wa = ldw4<F32>(wb, rb + vz);
  for (int kg = 0; kg < nk; kg += 8) {
    float4 wn = ldw4<F32>(wb, rb + kg + 4 + vz);
    float a0 = sb[(kg + 0) * 64 + lane], a1 = sb[(kg + 1) * 64 + lane],
          a2 = sb[(kg + 2) * 64 + lane], a3 = sb[(kg + 3) * 64 + lane];
    r0 = fmaf(wa.w, a3, fmaf(wa.z, a2, fmaf(wa.y, a1, fmaf(wa.x, a0, r0))));
    int kn = (kg + 8 < nk) ? kg + 8 : kg;
    wa = ldw4<F32>(wb, rb + kn + vz);
    float b0 = sb[(kg + 4) * 64 + lane], b1 = sb[(kg + 5) * 64 + lane],
          b2 = sb[(kg + 6) * 64 + lane], b3 = sb[(kg + 7) * 64 + lane];
    r0 = fmaf(wn.w, b3, fmaf(wn.z, b2, fmaf(wn.y, b1, fmaf(wn.x, b0, r0))));
  }
}

// ---------------- ws layout (float offsets), ~39.5 MB ----------------
constexpr size_t OBAR  = 0;                       // [32]=gen, [64]=dtype flag
constexpr size_t OFLG  = OBAR  + 128;             // per-wg arrival flags 256*32 ints
constexpr size_t OASUM = OFLG  + 8192;            // att_sum [b][t]     32768
constexpr size_t ODEC  = OASUM + 32768;           // dec0   [b][h]      32768
constexpr size_t OH0   = ODEC  + 32768;           // h0T    [h][b]      32768
constexpr size_t OH1   = OH0   + 32768;           // h1T    [h][b]      32768
constexpr size_t OPO   = OH1   + 32768;           // poT    [n][b]      10240
constexpr size_t OZEND = OPO   + 10240;
constexpr int    ZERO_SPAN_N = (int)OZEND;
constexpr size_t OPRV  = OZEND;                   // prev_w [b][t]      32768
constexpr size_t OERG  = OPRV  + 32768;           // erg    [b][t]      32768
constexpr size_t OX1   = OERG  + 32768;           // x1T    [n][b]      16384
constexpr size_t OX2   = OX1   + 16384;           // x2T    [n][b]      32768
constexpr size_t OATTC = OX2   + 32768;           // attcT  [c][b]      32768
constexpr size_t OMM   = OATTC + 32768;           // M[h][32] f32       16384
constexpr size_t OGI0  = OMM   + 16384;           // gi0p [4][1536][64] 393216 (setup alias: encT)
constexpr size_t OGH0  = OGI0  + 393216;          // gh0p               196608 (first 32768 double as dec1)
constexpr size_t OGH1  = OGH0  + 196608;          // gh1p               196608
constexpr size_t OGI1  = OGH1  + 196608;          // gi1p               393216
constexpr size_t OPM   = OGI1  + 393216;          // pm bf16 (16.7M u16 = 8388608 slots)
constexpr size_t OTOT  = OPM   + 8388608;

// ---------------- fence-free flag barrier ----------------
__device__ __forceinline__ void fastbar(int* flags, int* gen, int target,
                                        int wg, int tid) {
  __syncthreads();
  if (tid == 0) st_sc(flags + wg * 32, target);
  if (wg == 0) {
    if (tid < 64) {
      int i0 = tid * 4;
      for (;;) {
        int ok = (ld_sc(flags + (i0 + 0) * 32) >= target)
               & (ld_sc(flags + (i0 + 1) * 32) >= target)
               & (ld_sc(flags + (i0 + 2) * 32) >= target)
               & (ld_sc(flags + (i0 + 3) * 32) >= target);
        if (__ballot(ok) == 0xFFFFFFFFFFFFFFFFull) break;
      }
      if (tid == 0) st_sc(gen, target);
    }
    __syncthreads();
  } else {
    if (tid == 0) {
      while (ld_sc(gen) < target) {}
    }
    __syncthreads();
  }
}

// ---------------- setup kernels ----------------
__global__ void k_zero(float* p, int n) {
  for (int i = blockIdx.x * 256 + threadIdx.x; i < n; i += gridDim.x * 256) p[i] = 0.f;
}
__global__ void k_detect(int* flag, const u16* probe) {
  if (blockIdx.x != 0 || threadIdx.x != 0) return;
  int sane = 0;
  for (int i = 0; i < 256; i += 2) {
    u16 u = probe[i];
    int e = (u >> 7) & 0xFF;
    if (u == 0 || (e >= 97 && e <= 140)) ++sane;
  }
  *flag = (sane < 96) ? 1 : 0;   // 1 => inputs are raw f32
}
__global__ void k_prevw(float* prevw, const int* dlen) {
  int b = blockIdx.x;
  int len = dlen[b] >> 1;
  float inv = 1.f / (float)len;
  for (int i = threadIdx.x; i < 512; i += 256)
    prevw[b * 512 + i] = (i < len) ? inv : 0.f;
}
template<bool F32>
__global__ void k_cvtT512(const int* flag, float* dst, const void* src) {
  if (*flag != (F32 ? 1 : 0)) return;
  for (int i = blockIdx.x * 256 + threadIdx.x; i < 262144; i += gridDim.x * 256) {
    int c = i >> 9, h = i & 511;
    dst[i] = ldw<F32>(src, (size_t)h * 512 + c);
  }
}
template<bool F32>
__global__ void k_mmat(const int* flag, float* M, const void* locw, const void* convw) {
  if (*flag != (F32 ? 1 : 0)) return;
  int i = blockIdx.x * 256 + threadIdx.x;
  if (i >= 16384) return;
  int h = i >> 5, k = i & 31;
  float acc = 0.f;
  if (k < 31) {
    for (int c = 0; c < 32; ++c)
      acc = fmaf(ldw<F32>(locw, h * 32 + c), ldw<F32>(convw, c * 31 + k), acc);
  }
  M[i] = acc;
}
template<bool F32>
__global__ __launch_bounds__(256) void k_pm(const int* flag, u16* pm, const void* enc,
                                            const float* encwT, const void* encb) {
  if (*flag != (F32 ? 1 : 0)) return;
  __shared__ float encf[16 * 512];
  int row0 = blockIdx.x * 16;
  int tid = threadIdx.x;
  for (int i = tid; i < 16 * 512; i += 256) {
    int r = i >> 9, c = i & 511;
    encf[i] = ldw<F32>(enc, (size_t)(row0 + r) * 512 + c);
  }
  __syncthreads();
  float a0[16], a1[16];
  float bb0 = ldw<F32>(encb, tid), bb1 = ldw<F32>(encb, tid + 256);
#pragma unroll
  for (int r = 0; r < 16; ++r) { a0[r] = bb0; a1[r] = bb1; }
  for (int c = 0; c < 512; ++c) {
    float w0 = encwT[c * 512 + tid];
    float w1 = encwT[c * 512 + 256 + tid];
#pragma unroll
    for (int r = 0; r < 16; ++r) {
      float a = encf[r * 512 + c];
      a0[r] = fmaf(w0, a, a0[r]);
      a1[r] = fmaf(w1, a, a1[r]);
    }
  }
#pragma unroll
  for (int r = 0; r < 16; ++r) {
    pm[(size_t)(row0 + r) * 512 + tid]       = f2b(a0[r]);
    pm[(size_t)(row0 + r) * 512 + 256 + tid] = f2b(a1[r]);
  }
}

// ---------------- main persistent kernel ----------------
struct KP {
  const void* __restrict__ enc;
  const int* __restrict__ dlen;
  const u16* __restrict__ pm;          // internal bf16
  const void* __restrict__ wih0; const void* __restrict__ whh0;
  const void* __restrict__ wih1; const void* __restrict__ whh1;
  const void* __restrict__ adec; const void* __restrict__ outw;
  const void* __restrict__ pnw2; const void* __restrict__ pnw1;
  const void* __restrict__ pnb1; const void* __restrict__ pnb2;
  const void* __restrict__ bih0; const void* __restrict__ bhh0;
  const void* __restrict__ bih1; const void* __restrict__ bhh1;
  const void* __restrict__ outb; const void* __restrict__ vw;
  const float* __restrict__ Mg;
  int* __restrict__ bar;               // [32]=gen, [64]=dtype
  int* __restrict__ flags;             // 256 * 32 ints
  float* __restrict__ asum; float* __restrict__ dec;
  float* __restrict__ h0T;  float* __restrict__ h1T;  float* __restrict__ poT;
  float* __restrict__ prevw; float* __restrict__ erg;
  float* __restrict__ x1T;  float* __restrict__ x2T;  float* __restrict__ attcT;
  float* __restrict__ gi0p; float* __restrict__ gh0p;
  float* __restrict__ gh1p; float* __restrict__ gi1p;
  void* __restrict__ out;              // out_o at elem 0; out_a at elem 5242880
};

template<bool F32>
__global__ __launch_bounds__(256, 1) void k_loop(KP p) {
  if (*(const volatile int*)(p.bar + 64) != (F32 ? 1 : 0)) return;  // wrong-dtype variant exits
  __shared__ float stg[16384];       // 64 KB activation staging buffer
  __shared__ u16  M_u[32 * 512];
  __shared__ float dec_s[512];
  __shared__ float v_s[512];
  __shared__ float wq[160];
  __shared__ float sm[512];
  __shared__ float red[8];

  const int wg = blockIdx.x, tid = threadIdx.x;
  const int lane = tid & 63;
  const int wv = __builtin_amdgcn_readfirstlane(tid >> 6);
  const int wflat = wg * 4 + wv;
  const int b_att = wg >> 2, q = wg & 3, t0 = q * 128;
  const int trow = tid >> 6, hcol = tid & 63;
  float* dec1 = p.gh0p;              // dec partial 1 (region free between S4-read and S3-write)
  int* genp = p.bar + 32;
  int bt = 0;
  int vz;                            // opaque VGPR zero: forces VMEM path for weights
  asm volatile("v_mov_b32 %0, 0" : "=v"(vz));

  for (int i = tid; i < 32 * 512; i += 256) {
    int k = i >> 9, h = i & 511;
    M_u[i] = f2b(p.Mg[h * 32 + k]);
  }
  for (int i = tid; i < 512; i += 256) v_s[i] = ldw<F32>(p.vw, i);
  __syncthreads();

  for (int t = 0; t < 512; ++t) {
    // ===== S1: attention energies (+ prenet-1 from LDS-staged poT) =====
    if (wg < 64) stage_n(stg, p.poT, 10240, tid);   // poT [160][64] shared by 4 waves
    if (tid < 158) {
      int g = t0 - 15 + tid;
      wq[tid] = (g >= 0 && g < 512) ? ldf_sc(p.prevw + b_att * 512 + g) : 0.f;
    }
    for (int i = tid; i < 512; i += 256)
      dec_s[i] = ldf_sc(p.dec + b_att * 512 + i) + ldf_sc(dec1 + b_att * 512 + i);
    __syncthreads();
    if (wg < 64) {
      int n = wg * 4 + wv;
      float a = 0.f;
      dot1<F32>(a, stg, p.pnw1, (size_t)n * 160, 160, lane, vz);
      a += ldw<F32>(p.pnb1, n);
      stf_sc(p.x1T + n * 64 + lane, fmaxf(a, 0.f));
    }
    {
      float wreg[62];
#pragma unroll
      for (int i = 0; i < 62; ++i) wreg[i] = wq[trow * 32 + i];
      float acc[32];
#pragma unroll
      for (int s = 0; s < 32; ++s) acc[s] = 0.f;
      const u16* pmb = p.pm + ((size_t)(b_att * 512 + t0 + trow * 32)) * 512;
      for (int j = 0; j < 8; ++j) {
        int hj = hcol + 64 * j;
        float Mreg[31];
#pragma unroll
        for (int k = 0; k < 31; ++k) Mreg[k] = b2f(M_u[k * 512 + hj]);
        float dj = dec_s[hj], vj = v_s[hj];
#pragma unroll
        for (int s = 0; s < 32; ++s) {
          float u = dj;
#pragma unroll
          for (int k = 0; k < 31; ++k) u = fmaf(Mreg[k], wreg[s + k], u);
          u += b2f(pmb[s * 512 + hj]);
          acc[s] = fmaf(vj, tanh_f(u), acc[s]);
        }
      }
#pragma unroll
      for (int s = 0; s < 32; ++s) {
        float v = acc[s];
#pragma unroll
        for (int off = 32; off; off >>= 1) v += __shfl_xor(v, off, 64);
        if (hcol == 0) sm[trow * 32 + s] = v;
      }
      __syncthreads();
      if (tid < 128) stf_sc(p.erg + b_att * 512 + t0 + tid, sm[tid]);
    }
    fastbar(p.flags, genp, ++bt, wg, tid);

    // ===== S2: softmax/out_a | att_c (vectorized, tau-split) | prenet-2 =====
    if (wg < 64) {
      int b = wg;
      int len = p.dlen[b] >> 1;
      float e0 = ldf_sc(p.erg + b * 512 + tid), e1 = ldf_sc(p.erg + b * 512 + 256 + tid);
      bool v0 = tid < len, v1 = (256 + tid) < len;
      float mx = fmaxf(v0 ? e0 : -1e30f, v1 ? e1 : -1e30f);
#pragma unroll
      for (int off = 32; off; off >>= 1) mx = fmaxf(mx, __shfl_xor(mx, off, 64));
      if (lane == 0) red[wv] = mx;
      __syncthreads();
      mx = fmaxf(fmaxf(red[0], red[1]), fmaxf(red[2], red[3]));
      float x0 = v0 ? __expf(e0 - mx) : 0.f;
      float x1 = v1 ? __expf(e1 - mx) : 0.f;
      float s = x0 + x1;
#pragma unroll
      for (int off = 32; off; off >>= 1) s += __shfl_xor(s, off, 64);
      if (lane == 0) red[4 + wv] = s;
      __syncthreads();
      s = red[4] + red[5] + red[6] + red[7];
      float inv = 1.f / s;
      float w0 = x0 * inv, w1 = x1 * inv;
      stout<F32>(p.out, 5242880 + (size_t)b * 262144 + (size_t)tid * 512 + t, w0);
      stout<F32>(p.out, 5242880 + (size_t)b * 262144 + (size_t)(tid + 256) * 512 + t, w1);
      float s0 = p.asum[b * 512 + tid] + w0;
      float s1 = p.asum[b * 512 + 256 + tid] + w1;
      p.asum[b * 512 + tid] = s0;          stf_sc(p.prevw + b * 512 + tid, s0);
      p.asum[b * 512 + 256 + tid] = s1;    stf_sc(p.prevw + b * 512 + 256 + tid, s1);
    } else if (wg < 192) {
      int idx = wg - 64, b = idx >> 1, half = idx & 1;
      int len = p.dlen[b] >> 1;
      float e0 = ldf_sc(p.erg + b * 512 + tid), e1 = ldf_sc(p.erg + b * 512 + 256 + tid);
      bool v0 = tid < len, v1 = (256 + tid) < len;
      float mx = fmaxf(v0 ? e0 : -1e30f, v1 ? e1 : -1e30f);
#pragma unroll
      for (int off = 32; off; off >>= 1) mx = fmaxf(mx, __shfl_xor(mx, off, 64));
      if (lane == 0) red[wv] = mx;
      __syncthreads();
      mx = fmaxf(fmaxf(red[0], red[1]), fmaxf(red[2], red[3]));
      float x0 = v0 ? __expf(e0 - mx) : 0.f;
      float x1 = v1 ? __expf(e1 - mx) : 0.f;
      float s = x0 + x1;
#pragma unroll
      for (int off = 32; off; off >>= 1) s += __shfl_xor(s, off, 64);
      if (lane == 0) red[4 + wv] = s;
      __syncthreads();
      s = red[4] + red[5] + red[6] + red[7];
      float inv = 1.f / s;
      sm[tid] = x0 * inv; sm[256 + tid] = x1 * inv;
      __syncthreads();
      // att_c: lane owns 4 consecutive channels (float4 loads), wave owns 128 taus
      int c4 = half * 256 + lane * 4;
      size_t eb = (size_t)b * 262144 + c4;
      float4 ac[8];
#pragma unroll
      for (int i = 0; i < 8; ++i) ac[i] = make_float4(0.f, 0.f, 0.f, 0.f);
      int tb = wv * 128;
      for (int tt = 0; tt < 128; tt += 8) {
#pragma unroll
        for (int i = 0; i < 8; ++i) {
          float4 e = ldw4<F32>(p.enc, eb + (size_t)(tb + tt + i) * 512);
          float w = sm[tb + tt + i];
          ac[i].x = fmaf(w, e.x, ac[i].x);
          ac[i].y = fmaf(w, e.y, ac[i].y);
          ac[i].z = fmaf(w, e.z, ac[i].z);
          ac[i].w = fmaf(w, e.w, ac[i].w);
        }
      }
      float4 ssum;
      ssum.x = ((ac[0].x + ac[1].x) + (ac[2].x + ac[3].x)) + ((ac[4].x + ac[5].x) + (ac[6].x + ac[7].x));
      ssum.y = ((ac[0].y + ac[1].y) + (ac[2].y + ac[3].y)) + ((ac[4].y + ac[5].y) + (ac[6].y + ac[7].y));
      ssum.z = ((ac[0].z + ac[1].z) + (ac[2].z + ac[3].z)) + ((ac[4].z + ac[5].z) + (ac[6].z + ac[7].z));
      ssum.w = ((ac[0].w + ac[1].w) + (ac[2].w + ac[3].w)) + ((ac[4].w + ac[5].w) + (ac[6].w + ac[7].w));
      __syncthreads();                      // sm reads done before stg reuse
      *(float4*)&stg[wv * 256 + lane * 4] = ssum;   // partial per wave
      __syncthreads();
      float r = stg[tid] + stg[256 + tid] + stg[512 + tid] + stg[768 + tid];
      stf_sc(p.attcT + (half * 256 + tid) * 64 + b, r);
    } else {
      stage_n(stg, p.x1T, 16384, tid);           // x1T [256][64] shared by 4 waves
      __syncthreads();
      int idx = wg - 192;
      int n0 = (idx * 4 + wv) * 2;
      float xa = 0.f, xb = 0.f;
      dot2<F32>(xa, xb, stg, p.pnw2, (size_t)n0 * 256, (size_t)(n0 + 1) * 256, 256, lane, vz);
      xa += ldw<F32>(p.pnb2, n0); xb += ldw<F32>(p.pnb2, n0 + 1);
      stf_sc(p.x2T + n0 * 64 + lane,       fmaxf(xa, 0.f));
      stf_sc(p.x2T + (n0 + 1) * 64 + lane, fmaxf(xb, 0.f));
    }
    fastbar(p.flags, genp, ++bt, wg, tid);

    // ===== S3: gi0 | gh0 | gh1 — wg stages one 64KB k-part; waves share it =====
    {
      const float* src; const void* wb; float* dst;
      int n0, wstride, wc0;
      if (wg < 128) {               // gi0: kpart = wg&3, 32 n-groups
        int kpart = wg & 3, ngrp = wg >> 2;
        src = ((kpart < 2) ? p.x2T : p.attcT) + (kpart & 1) * 16384;
        wb = p.wih0; wstride = 1024;
        wc0 = (kpart >> 1) * 512 + (kpart & 1) * 256;
        n0 = (ngrp * 4 + wv) * 12;
        dst = p.gi0p + ((size_t)kpart * 1536 + n0) * 64;
      } else if (wg < 192) {        // gh0
        int idx = wg - 128, kpart = idx & 1, ngrp = idx >> 1;
        src = p.h0T + kpart * 16384;
        wb = p.whh0; wstride = 512; wc0 = kpart * 256;
        n0 = (ngrp * 4 + wv) * 12;
        dst = p.gh0p + ((size_t)kpart * 1536 + n0) * 64;
      } else {                      // gh1
        int idx = wg - 192, kpart = idx & 1, ngrp = idx >> 1;
        src = p.h1T + kpart * 16384;
        wb = p.whh1; wstride = 512; wc0 = kpart * 256;
        n0 = (ngrp * 4 + wv) * 12;
        dst = p.gh1p + ((size_t)kpart * 1536 + n0) * 64;
      }
      stage_n(stg, src, 16384, tid);
      __syncthreads();
      float acc[12];
#pragma unroll
      for (int i = 0; i < 12; ++i) acc[i] = 0.f;
      dot12<F32>(acc, stg, wb, (size_t)n0 * wstride + wc0, wstride, 256, lane, vz);
#pragma unroll
      for (int i = 0; i < 12; ++i) stf_sc(dst + (size_t)i * 64 + lane, acc[i]);
    }
    fastbar(p.flags, genp, ++bt, wg, tid);

    // ===== S4: GRU0 combine -> h0' =====
    if (wg < 128) {
      int e = wg * 256 + tid;
      int h = e >> 6, b = e & 63;
      float ir = ldf_sc(p.gi0p + h * 64 + b) + ldf_sc(p.gi0p + (1536 + h) * 64 + b)
               + ldf_sc(p.gi0p + (3072 + h) * 64 + b) + ldf_sc(p.gi0p + (4608 + h) * 64 + b)
               + ldw<F32>(p.bih0, h);
      float iz = ldf_sc(p.gi0p + (512 + h) * 64 + b) + ldf_sc(p.gi0p + (2048 + h) * 64 + b)
               + ldf_sc(p.gi0p + (3584 + h) * 64 + b) + ldf_sc(p.gi0p + (5120 + h) * 64 + b)
               + ldw<F32>(p.bih0, 512 + h);
      float in = ldf_sc(p.gi0p + (1024 + h) * 64 + b) + ldf_sc(p.gi0p + (2560 + h) * 64 + b)
               + ldf_sc(p.gi0p + (4096 + h) * 64 + b) + ldf_sc(p.gi0p + (5632 + h) * 64 + b)
               + ldw<F32>(p.bih0, 1024 + h);
      float hr = ldf_sc(p.gh0p + h * 64 + b) + ldf_sc(p.gh0p + (1536 + h) * 64 + b)
               + ldw<F32>(p.bhh0, h);
      float hz = ldf_sc(p.gh0p + (512 + h) * 64 + b) + ldf_sc(p.gh0p + (2048 + h) * 64 + b)
               + ldw<F32>(p.bhh0, 512 + h);
      float hn = ldf_sc(p.gh0p + (1024 + h) * 64 + b) + ldf_sc(p.gh0p + (2560 + h) * 64 + b)
               + ldw<F32>(p.bhh0, 1024 + h);
      float r = sig_f(ir + hr), z = sig_f(iz + hz);
      float nn = tanh_f(in + r * hn);
      float ho = ldf_sc(p.h0T + h * 64 + b);
      stf_sc(p.h0T + h * 64 + b, (1.f - z) * nn + z * ho);
    }
    fastbar(p.flags, genp, ++bt, wg, tid);

    // ===== S5: gi1 | dec partials (both halves in parallel) =====
    if (wg < 128) {                 // gi1: kpart = wg&3 (128-wide), 32 n-groups
      int kpart = wg & 3, ngrp = wg >> 2;
      stage_n(stg, p.h0T + kpart * 8192, 8192, tid);
      __syncthreads();
      int n0 = (ngrp * 4 + wv) * 12;
      float acc[12];
#pragma unroll
      for (int i = 0; i < 12; ++i) acc[i] = 0.f;
      dot12<F32>(acc, stg, p.wih1, (size_t)n0 * 512 + kpart * 128, 512, 128, lane, vz);
#pragma unroll
      for (int i = 0; i < 12; ++i)
        stf_sc(p.gi1p + ((size_t)kpart * 1536 + n0 + i) * 64 + lane, acc[i]);
    } else {                        // dec partials: wgs 128-191 -> chunk0, 192-255 -> chunk1
      int g = wg - 128;
      int cpart = g >> 6;
      int u = (g & 63) * 4 + wv, n0 = u * 2;
      stage_n(stg, p.h0T + cpart * 16384, 16384, tid);
      __syncthreads();
      float r0 = 0.f, r1 = 0.f;
      dot2<F32>(r0, r1, stg, p.adec, (size_t)n0 * 512 + cpart * 256,
                (size_t)(n0 + 1) * 512 + cpart * 256, 256, lane, vz);
      float* dst = cpart ? dec1 : p.dec;
      stf_sc(dst + lane * 512 + n0,     r0);
      stf_sc(dst + lane * 512 + n0 + 1, r1);
    }
    fastbar(p.flags, genp, ++bt, wg, tid);

    // ===== S6: GRU1 combine -> h1' =====
    if (wg < 128) {
      int e = wg * 256 + tid;
      int h = e >> 6, b = e & 63;
      float ir = ldf_sc(p.gi1p + h * 64 + b) + ldf_sc(p.gi1p + (1536 + h) * 64 + b)
               + ldf_sc(p.gi1p + (3072 + h) * 64 + b) + ldf_sc(p.gi1p + (4608 + h) * 64 + b)
               + ldw<F32>(p.bih1, h);
      float iz = ldf_sc(p.gi1p + (512 + h) * 64 + b) + ldf_sc(p.gi1p + (2048 + h) * 64 + b)
               + ldf_sc(p.gi1p + (3584 + h) * 64 + b) + ldf_sc(p.gi1p + (5120 + h) * 64 + b)
               + ldw<F32>(p.bih1, 512 + h);
      float in = ldf_sc(p.gi1p + (1024 + h) * 64 + b) + ldf_sc(p.gi1p + (2560 + h) * 64 + b)
               + ldf_sc(p.gi1p + (4096 + h) * 64 + b) + ldf_sc(p.gi1p + (5632 + h) * 64 + b)
               + ldw<F32>(p.bih1, 1024 + h);
      float hr = ldf_sc(p.gh1p + h * 64 + b) + ldf_sc(p.gh1p + (1536 + h) * 64 + b)
               + ldw<F32>(p.bhh1, h);
      float hz = ldf_sc(p.gh1p + (512 + h) * 64 + b) + ldf_sc(p.gh1p + (2048 + h) * 64 + b)
               + ldw<F32>(p.bhh1, 512 + h);
      float hn = ldf_sc(p.gh1p + (1024 + h) * 64 + b) + ldf_sc(p.gh1p + (2560 + h) * 64 + b)
               + ldw<F32>(p.bhh1, 1024 + h);
      float r = sig_f(ir + hr), z = sig_f(iz + hz);
      float nn = tanh_f(in + r * hn);
      float ho = ldf_sc(p.h1T + h * 64 + b);
      stf_sc(p.h1T + h * 64 + b, (1.f - z) * nn + z * ho);
    }
    fastbar(p.flags, genp, ++bt, wg, tid);

    // ===== S7: out = Wout @ [h1' ; att_c] + b — chunked LDS staging =====
    if (wg < 40) {
      int n = wg * 4 + wv;
      float r = 0.f;
      for (int c = 0; c < 4; ++c) {
        const float* src = ((c < 2) ? p.h1T : p.attcT) + (c & 1) * 16384;
        stage_n(stg, src, 16384, tid);
        __syncthreads();
        dot1<F32>(r, stg, p.outw, (size_t)n * 1024 + c * 256, 256, lane, vz);
        __syncthreads();
      }
      float acc = r + ldw<F32>(p.outb, n);
      stf_sc(p.poT + n * 64 + lane, acc);
      stout<F32>(p.out, (size_t)lane * 81920 + (size_t)(n >> 1) * 1024 + t * 2 + (n & 1), acc);
    }
    fastbar(p.flags, genp, ++bt, wg, tid);
  }
}

// ---------------- host launcher ----------------
extern "C" void kernel_launch(void* const* d_in, const int* in_sizes, int n_in,
                              void* d_out, int out_size, void* d_ws, size_t ws_size,
                              hipStream_t stream) {
  (void)in_sizes; (void)n_in; (void)out_size; (void)ws_size;
  const void* enc   = d_in[0];
  const int*  dlen  = (const int*)d_in[1];
  const void* pnw1  = d_in[2];
  const void* pnb1  = d_in[3];
  const void* pnw2  = d_in[4];
  const void* pnb2  = d_in[5];
  const void* aencw = d_in[6];
  const void* aencb = d_in[7];
  const void* adecw = d_in[8];
  const void* aconv = d_in[9];
  const void* alocw = d_in[10];
  const void* avw   = d_in[11];
  // d_in[12] = att_v_b: softmax-invariant -> unused
  const void* wih0  = d_in[13];
  const void* whh0  = d_in[14];
  const void* bih0  = d_in[15];
  const void* bhh0  = d_in[16];
  const void* wih1  = d_in[17];
  const void* whh1  = d_in[18];
  const void* bih1  = d_in[19];
  const void* bhh1  = d_in[20];
  const void* outw  = d_in[21];
  const void* outb  = d_in[22];

  float* W = (float*)d_ws;
  int* flag = (int*)(W + OBAR) + 64;
  dim3 blk(256);

  k_zero<<<256, blk, 0, stream>>>(W + OBAR, ZERO_SPAN_N);
  k_zero<<<64, blk, 0, stream>>>(W + OGH0, 32768);   // dec1 initial zero
  k_detect<<<1, blk, 0, stream>>>(flag, (const u16*)pnw1);
  k_prevw<<<64, blk, 0, stream>>>(W + OPRV, dlen);
  // dual-dtype setup (wrong variant self-disables via flag)
  k_mmat<false><<<64, blk, 0, stream>>>(flag, W + OMM, alocw, aconv);
  k_mmat<true ><<<64, blk, 0, stream>>>(flag, W + OMM, alocw, aconv);
  k_cvtT512<false><<<512, blk, 0, stream>>>(flag, W + OGI0, aencw);
  k_cvtT512<true ><<<512, blk, 0, stream>>>(flag, W + OGI0, aencw);
  k_pm<false><<<2048, blk, 0, stream>>>(flag, (u16*)(W + OPM), enc, W + OGI0, aencb);
  k_pm<true ><<<2048, blk, 0, stream>>>(flag, (u16*)(W + OPM), enc, W + OGI0, aencb);

  KP kp;
  kp.enc = enc; kp.dlen = dlen;
  kp.pm = (const u16*)(W + OPM);
  kp.wih0 = wih0; kp.whh0 = whh0;
  kp.wih1 = wih1; kp.whh1 = whh1;
  kp.adec = adecw; kp.outw = outw;
  kp.pnw2 = pnw2; kp.pnw1 = pnw1;
  kp.pnb1 = pnb1; kp.pnb2 = pnb2;
  kp.bih0 = bih0; kp.bhh0 = bhh0;
  kp.bih1 = bih1; kp.bhh1 = bhh1;
  kp.outb = outb; kp.vw = avw;
  kp.Mg = W + OMM;
  kp.bar = (int*)(W + OBAR);
  kp.flags = (int*)(W + OFLG);
  kp.asum = W + OASUM; kp.dec = W + ODEC;
  kp.h0T = W + OH0; kp.h1T = W + OH1; kp.poT = W + OPO;
  kp.prevw = W + OPRV; kp.erg = W + OERG;
  kp.x1T = W + OX1; kp.x2T = W + OX2; kp.attcT = W + OATTC;
  kp.gi0p = W + OGI0; kp.gh0p = W + OGH0;
  kp.gh1p = W + OGH1; kp.gi1p = W + OGI1;
  kp.out = d_out;

  // both variants launched; the wrong-dtype one exits before touching the barrier
  k_loop<false><<<dim3(256), blk, 0, stream>>>(kp);
  k_loop<true ><<<dim3(256), blk, 0, stream>>>(kp);
}

// Round 5
// 95072.809 us; speedup vs baseline: 4.0816x; 1.1592x over previous
//
#include <hip/hip_runtime.h>
#include <hip/hip_bf16.h>

typedef unsigned short u16;

// ---------------- constants ----------------
// B=64, T=512, C=512, H=512, D=80, RF=2, PRE_IN=160, PRE_INNER=256, CONV_CH=32, K=31

__device__ __forceinline__ float b2f(u16 u) {
  return __uint_as_float(((unsigned)u) << 16);
}
__device__ __forceinline__ u16 f2b(float f) {   // RNE f32->bf16
  unsigned u = __float_as_uint(f);
  u += 0x7fffu + ((u >> 16) & 1u);
  return (u16)(u >> 16);
}
template<bool F32>
__device__ __forceinline__ float ldw(const void* p, size_t i) {
  return F32 ? ((const float*)p)[i] : b2f(((const u16*)p)[i]);
}
template<bool F32>
__device__ __forceinline__ float4 ldw4(const void* p, size_t i) {
  if (F32) {
    return *(const float4*)((const float*)p + i);
  } else {
    uint2 u = *(const uint2*)((const u16*)p + i);
    float4 r;
    r.x = __uint_as_float(u.x << 16);
    r.y = __uint_as_float(u.x & 0xffff0000u);
    r.z = __uint_as_float(u.y << 16);
    r.w = __uint_as_float(u.y & 0xffff0000u);
    return r;
  }
}
template<bool F32>
__device__ __forceinline__ void stout(void* p, size_t i, float v) {
  if (F32) ((float*)p)[i] = v; else ((u16*)p)[i] = f2b(v);
}
__device__ __forceinline__ float frcp(float x) { return __builtin_amdgcn_rcpf(x); }
__device__ __forceinline__ float tanh_f(float x) {
  float e = __expf(2.f * x);
  return 1.f - 2.f * frcp(e + 1.f);     // inf-safe
}
__device__ __forceinline__ float sig_f(float x) { return frcp(1.f + __expf(-x)); }

// ---- relaxed agent-scope (MALL-coherent, fence-free) accessors ----
__device__ __forceinline__ void st_sc(int* p, int v) {
  __hip_atomic_store(p, v, __ATOMIC_RELAXED, __HIP_MEMORY_SCOPE_AGENT);
}
__device__ __forceinline__ int ld_sc(const int* p) {
  return __hip_atomic_load(p, __ATOMIC_RELAXED, __HIP_MEMORY_SCOPE_AGENT);
}
__device__ __forceinline__ void stf_sc(float* p, float v) {
  __hip_atomic_store(p, v, __ATOMIC_RELAXED, __HIP_MEMORY_SCOPE_AGENT);
}
__device__ __forceinline__ float ldf_sc(const float* p) {
  return __hip_atomic_load(p, __ATOMIC_RELAXED, __HIP_MEMORY_SCOPE_AGENT);
}

// Burst-copy n floats global->LDS; 512-thread version (8 loads in flight).
__device__ __forceinline__ void stage_n(float* lds, const float* src, int n, int tid) {
  int i = 0;
  for (; i + 4096 <= n; i += 4096) {
    float r[8];
#pragma unroll
    for (int j = 0; j < 8; ++j) r[j] = ldf_sc(src + i + tid + j * 512);
#pragma unroll
    for (int j = 0; j < 8; ++j) lds[i + tid + j * 512] = r[j];
  }
  for (; i < n; i += 2048) {
    float r[4];
#pragma unroll
    for (int j = 0; j < 4; ++j) r[j] = ldf_sc(src + i + tid + j * 512);
#pragma unroll
    for (int j = 0; j < 4; ++j) lds[i + tid + j * 512] = r[j];
  }
}

// ---- software-pipelined weight-streaming dot kernel ----
template<bool F32, int NR>
__device__ __forceinline__ void dotN(float* __restrict__ acc, const float* __restrict__ sb,
                                     const void* __restrict__ wb, size_t rb, int wstride,
                                     int nk, int lane, int vz) {
  float4 wa[NR], wn[NR];
#pragma unroll
  for (int i = 0; i < NR; ++i) wa[i] = ldw4<F32>(wb, rb + (size_t)i * wstride + vz);
  for (int kg = 0; kg < nk; kg += 8) {
#pragma unroll
    for (int i = 0; i < NR; ++i) wn[i] = ldw4<F32>(wb, rb + (size_t)i * wstride + kg + 4 + vz);
    float a0 = sb[(kg + 0) * 64 + lane], a1 = sb[(kg + 1) * 64 + lane],
          a2 = sb[(kg + 2) * 64 + lane], a3 = sb[(kg + 3) * 64 + lane];
#pragma unroll
    for (int i = 0; i < NR; ++i)
      acc[i] = fmaf(wa[i].w, a3, fmaf(wa[i].z, a2, fmaf(wa[i].y, a1, fmaf(wa[i].x, a0, acc[i]))));
    int kn = (kg + 8 < nk) ? kg + 8 : kg;
#pragma unroll
    for (int i = 0; i < NR; ++i) wa[i] = ldw4<F32>(wb, rb + (size_t)i * wstride + kn + vz);
    float b0 = sb[(kg + 4) * 64 + lane], b1 = sb[(kg + 5) * 64 + lane],
          b2 = sb[(kg + 6) * 64 + lane], b3 = sb[(kg + 7) * 64 + lane];
#pragma unroll
    for (int i = 0; i < NR; ++i)
      acc[i] = fmaf(wn[i].w, b3, fmaf(wn[i].z, b2, fmaf(wn[i].y, b1, fmaf(wn[i].x, b0, acc[i]))));
  }
}

// ---------------- ws layout (float offsets), ~39.5 MB ----------------
constexpr size_t OBAR  = 0;                       // [32]=gen, [64]=dtype flag
constexpr size_t OFLG  = OBAR  + 128;             // per-wg arrival flags 256*32 ints
constexpr size_t OASUM = OFLG  + 8192;            // att_sum [b][t]     32768
constexpr size_t ODEC  = OASUM + 32768;           // dec0   [b][h]      32768
constexpr size_t OH0   = ODEC  + 32768;           // h0T    [h][b]      32768
constexpr size_t OH1   = OH0   + 32768;           // h1T    [h][b]      32768
constexpr size_t OPO   = OH1   + 32768;           // poT    [n][b]      10240
constexpr size_t OZEND = OPO   + 10240;
constexpr int    ZERO_SPAN_N = (int)OZEND;
constexpr size_t OPRV  = OZEND;                   // prev_w [b][t]      32768
constexpr size_t OERG  = OPRV  + 32768;           // erg    [b][t]      32768
constexpr size_t OX1   = OERG  + 32768;           // x1T    [n][b]      16384
constexpr size_t OX2   = OX1   + 16384;           // x2T    [n][b]      32768
constexpr size_t OATTC = OX2   + 32768;           // attcT  [c][b]      32768
constexpr size_t OMM   = OATTC + 32768;           // M[h][32] f32       16384
constexpr size_t OGI0  = OMM   + 16384;           // gi0p [4][1536][64] 393216 (setup alias: encT)
constexpr size_t OGH0  = OGI0  + 393216;          // gh0p               196608 (first 32768 double as dec1)
constexpr size_t OGH1  = OGH0  + 196608;          // gh1p               196608
constexpr size_t OGI1  = OGH1  + 196608;          // gi1p               393216
constexpr size_t OPM   = OGI1  + 393216;          // pm bf16 (16.7M u16 = 8388608 slots)
constexpr size_t OTOT  = OPM   + 8388608;

// ---------------- fence-free flag barrier ----------------
__device__ __forceinline__ void fastbar(int* flags, int* gen, int target,
                                        int wg, int tid) {
  __syncthreads();
  if (tid == 0) st_sc(flags + wg * 32, target);
  if (wg == 0) {
    if (tid < 64) {
      int i0 = tid * 4;
      for (;;) {
        int ok = (ld_sc(flags + (i0 + 0) * 32) >= target)
               & (ld_sc(flags + (i0 + 1) * 32) >= target)
               & (ld_sc(flags + (i0 + 2) * 32) >= target)
               & (ld_sc(flags + (i0 + 3) * 32) >= target);
        if (__ballot(ok) == 0xFFFFFFFFFFFFFFFFull) break;
      }
      if (tid == 0) st_sc(gen, target);
    }
    __syncthreads();
  } else {
    if (tid == 0) {
      while (ld_sc(gen) < target) {}
    }
    __syncthreads();
  }
}

// ---------------- setup kernels (256 threads) ----------------
__global__ void k_zero(float* p, int n) {
  for (int i = blockIdx.x * 256 + threadIdx.x; i < n; i += gridDim.x * 256) p[i] = 0.f;
}
__global__ void k_detect(int* flag, const u16* probe) {
  if (blockIdx.x != 0 || threadIdx.x != 0) return;
  int sane = 0;
  for (int i = 0; i < 256; i += 2) {
    u16 u = probe[i];
    int e = (u >> 7) & 0xFF;
    if (u == 0 || (e >= 97 && e <= 140)) ++sane;
  }
  *flag = (sane < 96) ? 1 : 0;   // 1 => inputs are raw f32
}
__global__ void k_prevw(float* prevw, const int* dlen) {
  int b = blockIdx.x;
  int len = dlen[b] >> 1;
  float inv = 1.f / (float)len;
  for (int i = threadIdx.x; i < 512; i += 256)
    prevw[b * 512 + i] = (i < len) ? inv : 0.f;
}
template<bool F32>
__global__ void k_cvtT512(const int* flag, float* dst, const void* src) {
  if (*flag != (F32 ? 1 : 0)) return;
  for (int i = blockIdx.x * 256 + threadIdx.x; i < 262144; i += gridDim.x * 256) {
    int c = i >> 9, h = i & 511;
    dst[i] = ldw<F32>(src, (size_t)h * 512 + c);
  }
}
template<bool F32>
__global__ void k_mmat(const int* flag, float* M, const void* locw, const void* convw) {
  if (*flag != (F32 ? 1 : 0)) return;
  int i = blockIdx.x * 256 + threadIdx.x;
  if (i >= 16384) return;
  int h = i >> 5, k = i & 31;
  float acc = 0.f;
  if (k < 31) {
    for (int c = 0; c < 32; ++c)
      acc = fmaf(ldw<F32>(locw, h * 32 + c), ldw<F32>(convw, c * 31 + k), acc);
  }
  M[i] = acc;
}
template<bool F32>
__global__ __launch_bounds__(256) void k_pm(const int* flag, u16* pm, const void* enc,
                                            const float* encwT, const void* encb) {
  if (*flag != (F32 ? 1 : 0)) return;
  __shared__ float encf[16 * 512];
  int row0 = blockIdx.x * 16;
  int tid = threadIdx.x;
  for (int i = tid; i < 16 * 512; i += 256) {
    int r = i >> 9, c = i & 511;
    encf[i] = ldw<F32>(enc, (size_t)(row0 + r) * 512 + c);
  }
  __syncthreads();
  float a0[16], a1[16];
  float bb0 = ldw<F32>(encb, tid), bb1 = ldw<F32>(encb, tid + 256);
#pragma unroll
  for (int r = 0; r < 16; ++r) { a0[r] = bb0; a1[r] = bb1; }
  for (int c = 0; c < 512; ++c) {
    float w0 = encwT[c * 512 + tid];
    float w1 = encwT[c * 512 + 256 + tid];
#pragma unroll
    for (int r = 0; r < 16; ++r) {
      float a = encf[r * 512 + c];
      a0[r] = fmaf(w0, a, a0[r]);
      a1[r] = fmaf(w1, a, a1[r]);
    }
  }
#pragma unroll
  for (int r = 0; r < 16; ++r) {
    pm[(size_t)(row0 + r) * 512 + tid]       = f2b(a0[r]);
    pm[(size_t)(row0 + r) * 512 + 256 + tid] = f2b(a1[r]);
  }
}

// ---------------- main persistent kernel (512 threads = 8 waves) ----------------
struct KP {
  const void* __restrict__ enc;
  const int* __restrict__ dlen;
  const u16* __restrict__ pm;          // internal bf16
  const void* __restrict__ wih0; const void* __restrict__ whh0;
  const void* __restrict__ wih1; const void* __restrict__ whh1;
  const void* __restrict__ adec; const void* __restrict__ outw;
  const void* __restrict__ pnw2; const void* __restrict__ pnw1;
  const void* __restrict__ pnb1; const void* __restrict__ pnb2;
  const void* __restrict__ bih0; const void* __restrict__ bhh0;
  const void* __restrict__ bih1; const void* __restrict__ bhh1;
  const void* __restrict__ outb; const void* __restrict__ vw;
  const float* __restrict__ Mg;
  int* __restrict__ bar;               // [32]=gen, [64]=dtype
  int* __restrict__ flags;             // 256 * 32 ints
  float* __restrict__ asum; float* __restrict__ dec;
  float* __restrict__ h0T;  float* __restrict__ h1T;  float* __restrict__ poT;
  float* __restrict__ prevw; float* __restrict__ erg;
  float* __restrict__ x1T;  float* __restrict__ x2T;  float* __restrict__ attcT;
  float* __restrict__ gi0p; float* __restrict__ gh0p;
  float* __restrict__ gh1p; float* __restrict__ gi1p;
  void* __restrict__ out;              // out_o at elem 0; out_a at elem 5242880
};

template<bool F32>
__global__ __launch_bounds__(512, 2) void k_loop(KP p) {
  if (*(const volatile int*)(p.bar + 64) != (F32 ? 1 : 0)) return;  // wrong-dtype variant exits
  __shared__ float stg[16384];       // 64 KB activation staging buffer
  __shared__ u16  M_u[32 * 512];
  __shared__ float dec_s[512];
  __shared__ float v_s[512];
  __shared__ float wq[160];
  __shared__ float sm[512];
  __shared__ float red[16];

  const int wg = blockIdx.x, tid = threadIdx.x;
  const int lane = tid & 63;
  const int wv = __builtin_amdgcn_readfirstlane(tid >> 6);   // 0..7
  const int b_att = wg >> 2, q = wg & 3, t0 = q * 128;
  const int trow = tid >> 6;          // 0..7 (= wv)
  const int hcol = tid & 63;
  float* dec1 = p.gh0p;              // dec partial 1 (region free between S4-read and S3-write)
  int* genp = p.bar + 32;
  int bt = 0;
  int vz;                            // opaque VGPR zero: forces VMEM path for weights
  asm volatile("v_mov_b32 %0, 0" : "=v"(vz));

  for (int i = tid; i < 32 * 512; i += 512) {
    int k = i >> 9, h = i & 511;
    M_u[i] = f2b(p.Mg[h * 32 + k]);
  }
  for (int i = tid; i < 512; i += 512) v_s[i] = ldw<F32>(p.vw, i);
  __syncthreads();

  for (int t = 0; t < 512; ++t) {
    // ===== S1: attention energies (+ prenet-1 from LDS-staged poT) =====
    if (wg < 32) stage_n(stg, p.poT, 10240, tid);   // poT [160][64] shared by 8 waves
    if (tid < 158) {
      int g = t0 - 15 + tid;
      wq[tid] = (g >= 0 && g < 512) ? ldf_sc(p.prevw + b_att * 512 + g) : 0.f;
    }
    if (tid < 512)
      dec_s[tid] = ldf_sc(p.dec + b_att * 512 + tid) + ldf_sc(dec1 + b_att * 512 + tid);
    __syncthreads();
    if (wg < 32) {                    // prenet-1: 32 wgs x 8 waves = 256 outputs
      int n = wg * 8 + wv;
      float a[1] = {0.f};
      dotN<F32, 1>(a, stg, p.pnw1, (size_t)n * 160, 160, 160, lane, vz);
      stf_sc(p.x1T + n * 64 + lane, fmaxf(a[0] + ldw<F32>(p.pnb1, n), 0.f));
    }
    {
      // each wave owns 16 s-rows: s = trow*16 .. +16
      float wreg[46];
#pragma unroll
      for (int i = 0; i < 46; ++i) wreg[i] = wq[trow * 16 + i];
      float acc[16];
#pragma unroll
      for (int s = 0; s < 16; ++s) acc[s] = 0.f;
      const u16* pmb = p.pm + ((size_t)(b_att * 512 + t0 + trow * 16)) * 512;
      for (int j = 0; j < 8; ++j) {
        int hj = hcol + 64 * j;
        float Mreg[31];
#pragma unroll
        for (int k = 0; k < 31; ++k) Mreg[k] = b2f(M_u[k * 512 + hj]);
        float dj = dec_s[hj], vj = v_s[hj];
#pragma unroll
        for (int s = 0; s < 16; ++s) {
          float u = dj;
#pragma unroll
          for (int k = 0; k < 31; ++k) u = fmaf(Mreg[k], wreg[s + k], u);
          u += b2f(pmb[s * 512 + hj]);
          acc[s] = fmaf(vj, tanh_f(u), acc[s]);
        }
      }
#pragma unroll
      for (int s = 0; s < 16; ++s) {
        float v = acc[s];
#pragma unroll
        for (int off = 32; off; off >>= 1) v += __shfl_xor(v, off, 64);
        if (hcol == 0) sm[trow * 16 + s] = v;
      }
      __syncthreads();
      if (tid < 128) stf_sc(p.erg + b_att * 512 + t0 + tid, sm[tid]);
    }
    fastbar(p.flags, genp, ++bt, wg, tid);

    // ===== S2: softmax/out_a | att_c (8-wave tau-split) | prenet-2 =====
    if (wg < 64) {
      int b = wg;
      int len = p.dlen[b] >> 1;
      float e0 = ldf_sc(p.erg + b * 512 + tid);
      bool v0 = tid < len;
      float mx = v0 ? e0 : -1e30f;
#pragma unroll
      for (int off = 32; off; off >>= 1) mx = fmaxf(mx, __shfl_xor(mx, off, 64));
      if (lane == 0) red[wv] = mx;
      __syncthreads();
      mx = fmaxf(fmaxf(fmaxf(red[0], red[1]), fmaxf(red[2], red[3])),
                 fmaxf(fmaxf(red[4], red[5]), fmaxf(red[6], red[7])));
      float x0 = v0 ? __expf(e0 - mx) : 0.f;
      float s = x0;
#pragma unroll
      for (int off = 32; off; off >>= 1) s += __shfl_xor(s, off, 64);
      if (lane == 0) red[8 + wv] = s;
      __syncthreads();
      s = ((red[8] + red[9]) + (red[10] + red[11])) + ((red[12] + red[13]) + (red[14] + red[15]));
      float w0 = x0 * frcp(s);
      stout<F32>(p.out, 5242880 + (size_t)b * 262144 + (size_t)tid * 512 + t, w0);
      float s0 = p.asum[b * 512 + tid] + w0;
      p.asum[b * 512 + tid] = s0;
      stf_sc(p.prevw + b * 512 + tid, s0);
    } else if (wg < 192) {
      int idx = wg - 64, b = idx >> 1, half = idx & 1;
      int len = p.dlen[b] >> 1;
      float e0 = ldf_sc(p.erg + b * 512 + tid);
      bool v0 = tid < len;
      float mx = v0 ? e0 : -1e30f;
#pragma unroll
      for (int off = 32; off; off >>= 1) mx = fmaxf(mx, __shfl_xor(mx, off, 64));
      if (lane == 0) red[wv] = mx;
      __syncthreads();
      mx = fmaxf(fmaxf(fmaxf(red[0], red[1]), fmaxf(red[2], red[3])),
                 fmaxf(fmaxf(red[4], red[5]), fmaxf(red[6], red[7])));
      float x0 = v0 ? __expf(e0 - mx) : 0.f;
      float s = x0;
#pragma unroll
      for (int off = 32; off; off >>= 1) s += __shfl_xor(s, off, 64);
      if (lane == 0) red[8 + wv] = s;
      __syncthreads();
      s = ((red[8] + red[9]) + (red[10] + red[11])) + ((red[12] + red[13]) + (red[14] + red[15]));
      sm[tid] = x0 * frcp(s);
      __syncthreads();
      // att_c: lane owns 4 consecutive channels; wave owns 64 taus
      int c4 = half * 256 + lane * 4;
      size_t eb = (size_t)b * 262144 + c4;
      float4 ac[8];
#pragma unroll
      for (int i = 0; i < 8; ++i) ac[i] = make_float4(0.f, 0.f, 0.f, 0.f);
      int tb = wv * 64;
      for (int tt = 0; tt < 64; tt += 8) {
#pragma unroll
        for (int i = 0; i < 8; ++i) {
          float4 e = ldw4<F32>(p.enc, eb + (size_t)(tb + tt + i) * 512);
          float w = sm[tb + tt + i];
          ac[i].x = fmaf(w, e.x, ac[i].x);
          ac[i].y = fmaf(w, e.y, ac[i].y);
          ac[i].z = fmaf(w, e.z, ac[i].z);
          ac[i].w = fmaf(w, e.w, ac[i].w);
        }
      }
      float4 ssum;
      ssum.x = ((ac[0].x + ac[1].x) + (ac[2].x + ac[3].x)) + ((ac[4].x + ac[5].x) + (ac[6].x + ac[7].x));
      ssum.y = ((ac[0].y + ac[1].y) + (ac[2].y + ac[3].y)) + ((ac[4].y + ac[5].y) + (ac[6].y + ac[7].y));
      ssum.z = ((ac[0].z + ac[1].z) + (ac[2].z + ac[3].z)) + ((ac[4].z + ac[5].z) + (ac[6].z + ac[7].z));
      ssum.w = ((ac[0].w + ac[1].w) + (ac[2].w + ac[3].w)) + ((ac[4].w + ac[5].w) + (ac[6].w + ac[7].w));
      __syncthreads();                      // sm reads done before stg reuse
      *(float4*)&stg[wv * 256 + lane * 4] = ssum;   // 8 wave-partials x 256 ch
      __syncthreads();
      if (tid < 256) {
        float r = ((stg[tid] + stg[256 + tid]) + (stg[512 + tid] + stg[768 + tid]))
                + ((stg[1024 + tid] + stg[1280 + tid]) + (stg[1536 + tid] + stg[1792 + tid]));
        stf_sc(p.attcT + (half * 256 + tid) * 64 + b, r);
      }
    } else {
      stage_n(stg, p.x1T, 16384, tid);           // x1T [256][64] shared by 8 waves
      __syncthreads();
      int idx = wg - 192;                        // 64 wgs x 8 waves = 512 outputs
      int n = idx * 8 + wv;
      float a[1] = {0.f};
      dotN<F32, 1>(a, stg, p.pnw2, (size_t)n * 256, 256, 256, lane, vz);
      stf_sc(p.x2T + n * 64 + lane, fmaxf(a[0] + ldw<F32>(p.pnb2, n), 0.f));
    }
    fastbar(p.flags, genp, ++bt, wg, tid);

    // ===== S3: gi0 | gh0 | gh1 — wg stages one 64KB k-part; 8 waves share it =====
    {
      const float* src; const void* wb; float* dst;
      int n0, wstride, wc0;
      if (wg < 128) {               // gi0: kpart = wg&3, 32 n-groups of 48
        int kpart = wg & 3, ngrp = wg >> 2;
        src = ((kpart < 2) ? p.x2T : p.attcT) + (kpart & 1) * 16384;
        wb = p.wih0; wstride = 1024;
        wc0 = (kpart >> 1) * 512 + (kpart & 1) * 256;
        n0 = ngrp * 48 + wv * 6;
        dst = p.gi0p + ((size_t)kpart * 1536 + n0) * 64;
      } else if (wg < 192) {        // gh0
        int idx = wg - 128, kpart = idx & 1, ngrp = idx >> 1;
        src = p.h0T + kpart * 16384;
        wb = p.whh0; wstride = 512; wc0 = kpart * 256;
        n0 = ngrp * 48 + wv * 6;
        dst = p.gh0p + ((size_t)kpart * 1536 + n0) * 64;
      } else {                      // gh1
        int idx = wg - 192, kpart = idx & 1, ngrp = idx >> 1;
        src = p.h1T + kpart * 16384;
        wb = p.whh1; wstride = 512; wc0 = kpart * 256;
        n0 = ngrp * 48 + wv * 6;
        dst = p.gh1p + ((size_t)kpart * 1536 + n0) * 64;
      }
      stage_n(stg, src, 16384, tid);
      __syncthreads();
      float acc[6];
#pragma unroll
      for (int i = 0; i < 6; ++i) acc[i] = 0.f;
      dotN<F32, 6>(acc, stg, wb, (size_t)n0 * wstride + wc0, wstride, 256, lane, vz);
#pragma unroll
      for (int i = 0; i < 6; ++i) stf_sc(dst + (size_t)i * 64 + lane, acc[i]);
    }
    fastbar(p.flags, genp, ++bt, wg, tid);

    // ===== S4: GRU0 combine -> h0' =====
    if (wg < 64) {
      int e = wg * 512 + tid;
      int h = e >> 6, b = e & 63;
      float ir = ldf_sc(p.gi0p + h * 64 + b) + ldf_sc(p.gi0p + (1536 + h) * 64 + b)
               + ldf_sc(p.gi0p + (3072 + h) * 64 + b) + ldf_sc(p.gi0p + (4608 + h) * 64 + b)
               + ldw<F32>(p.bih0, h);
      float iz = ldf_sc(p.gi0p + (512 + h) * 64 + b) + ldf_sc(p.gi0p + (2048 + h) * 64 + b)
               + ldf_sc(p.gi0p + (3584 + h) * 64 + b) + ldf_sc(p.gi0p + (5120 + h) * 64 + b)
               + ldw<F32>(p.bih0, 512 + h);
      float in = ldf_sc(p.gi0p + (1024 + h) * 64 + b) + ldf_sc(p.gi0p + (2560 + h) * 64 + b)
               + ldf_sc(p.gi0p + (4096 + h) * 64 + b) + ldf_sc(p.gi0p + (5632 + h) * 64 + b)
               + ldw<F32>(p.bih0, 1024 + h);
      float hr = ldf_sc(p.gh0p + h * 64 + b) + ldf_sc(p.gh0p + (1536 + h) * 64 + b)
               + ldw<F32>(p.bhh0, h);
      float hz = ldf_sc(p.gh0p + (512 + h) * 64 + b) + ldf_sc(p.gh0p + (2048 + h) * 64 + b)
               + ldw<F32>(p.bhh0, 512 + h);
      float hn = ldf_sc(p.gh0p + (1024 + h) * 64 + b) + ldf_sc(p.gh0p + (2560 + h) * 64 + b)
               + ldw<F32>(p.bhh0, 1024 + h);
      float r = sig_f(ir + hr), z = sig_f(iz + hz);
      float nn = tanh_f(in + r * hn);
      float ho = ldf_sc(p.h0T + h * 64 + b);
      stf_sc(p.h0T + h * 64 + b, (1.f - z) * nn + z * ho);
    }
    fastbar(p.flags, genp, ++bt, wg, tid);

    // ===== S5: gi1 | dec partials (both halves in parallel) =====
    if (wg < 128) {                 // gi1: kpart = wg&3 (128-wide), 32 n-groups of 48
      int kpart = wg & 3, ngrp = wg >> 2;
      stage_n(stg, p.h0T + kpart * 8192, 8192, tid);
      __syncthreads();
      int n0 = ngrp * 48 + wv * 6;
      float acc[6];
#pragma unroll
      for (int i = 0; i < 6; ++i) acc[i] = 0.f;
      dotN<F32, 6>(acc, stg, p.wih1, (size_t)n0 * 512 + kpart * 128, 512, 128, lane, vz);
#pragma unroll
      for (int i = 0; i < 6; ++i)
        stf_sc(p.gi1p + ((size_t)kpart * 1536 + n0 + i) * 64 + lane, acc[i]);
    } else {                        // dec partials: wgs 128-191 -> chunk0, 192-255 -> chunk1
      int g = wg - 128;
      int cpart = g >> 6;
      int n = (g & 63) * 8 + wv;                 // one output per wave
      stage_n(stg, p.h0T + cpart * 16384, 16384, tid);
      __syncthreads();
      float r[1] = {0.f};
      dotN<F32, 1>(r, stg, p.adec, (size_t)n * 512 + cpart * 256, 512, 256, lane, vz);
      float* dst = cpart ? dec1 : p.dec;
      stf_sc(dst + lane * 512 + n, r[0]);
    }
    fastbar(p.flags, genp, ++bt, wg, tid);

    // ===== S6: GRU1 combine -> h1' =====
    if (wg < 64) {
      int e = wg * 512 + tid;
      int h = e >> 6, b = e & 63;
      float ir = ldf_sc(p.gi1p + h * 64 + b) + ldf_sc(p.gi1p + (1536 + h) * 64 + b)
               + ldf_sc(p.gi1p + (3072 + h) * 64 + b) + ldf_sc(p.gi1p + (4608 + h) * 64 + b)
               + ldw<F32>(p.bih1, h);
      float iz = ldf_sc(p.gi1p + (512 + h) * 64 + b) + ldf_sc(p.gi1p + (2048 + h) * 64 + b)
               + ldf_sc(p.gi1p + (3584 + h) * 64 + b) + ldf_sc(p.gi1p + (5120 + h) * 64 + b)
               + ldw<F32>(p.bih1, 512 + h);
      float in = ldf_sc(p.gi1p + (1024 + h) * 64 + b) + ldf_sc(p.gi1p + (2560 + h) * 64 + b)
               + ldf_sc(p.gi1p + (4096 + h) * 64 + b) + ldf_sc(p.gi1p + (5632 + h) * 64 + b)
               + ldw<F32>(p.bih1, 1024 + h);
      float hr = ldf_sc(p.gh1p + h * 64 + b) + ldf_sc(p.gh1p + (1536 + h) * 64 + b)
               + ldw<F32>(p.bhh1, h);
      float hz = ldf_sc(p.gh1p + (512 + h) * 64 + b) + ldf_sc(p.gh1p + (2048 + h) * 64 + b)
               + ldw<F32>(p.bhh1, 512 + h);
      float hn = ldf_sc(p.gh1p + (1024 + h) * 64 + b) + ldf_sc(p.gh1p + (2560 + h) * 64 + b)
               + ldw<F32>(p.bhh1, 1024 + h);
      float r = sig_f(ir + hr), z = sig_f(iz + hz);
      float nn = tanh_f(in + r * hn);
      float ho = ldf_sc(p.h1T + h * 64 + b);
      stf_sc(p.h1T + h * 64 + b, (1.f - z) * nn + z * ho);
    }
    fastbar(p.flags, genp, ++bt, wg, tid);

    // ===== S7: out = Wout @ [h1' ; att_c] + b — chunked LDS staging =====
    if (wg < 20) {
      int n = wg * 8 + wv;                       // 20 wgs x 8 waves = 160 outputs
      float r[1] = {0.f};
      for (int c = 0; c < 4; ++c) {
        const float* src = ((c < 2) ? p.h1T : p.attcT) + (c & 1) * 16384;
        stage_n(stg, src, 16384, tid);
        __syncthreads();
        dotN<F32, 1>(r, stg, p.outw, (size_t)n * 1024 + c * 256, 1024, 256, lane, vz);
        __syncthreads();
      }
      float acc = r[0] + ldw<F32>(p.outb, n);
      stf_sc(p.poT + n * 64 + lane, acc);
      stout<F32>(p.out, (size_t)lane * 81920 + (size_t)(n >> 1) * 1024 + t * 2 + (n & 1), acc);
    }
    fastbar(p.flags, genp, ++bt, wg, tid);
  }
}

// ---------------- host launcher ----------------
extern "C" void kernel_launch(void* const* d_in, const int* in_sizes, int n_in,
                              void* d_out, int out_size, void* d_ws, size_t ws_size,
                              hipStream_t stream) {
  (void)in_sizes; (void)n_in; (void)out_size; (void)ws_size;
  const void* enc   = d_in[0];
  const int*  dlen  = (const int*)d_in[1];
  const void* pnw1  = d_in[2];
  const void* pnb1  = d_in[3];
  const void* pnw2  = d_in[4];
  const void* pnb2  = d_in[5];
  const void* aencw = d_in[6];
  const void* aencb = d_in[7];
  const void* adecw = d_in[8];
  const void* aconv = d_in[9];
  const void* alocw = d_in[10];
  const void* avw   = d_in[11];
  // d_in[12] = att_v_b: softmax-invariant -> unused
  const void* wih0  = d_in[13];
  const void* whh0  = d_in[14];
  const void* bih0  = d_in[15];
  const void* bhh0  = d_in[16];
  const void* wih1  = d_in[17];
  const void* whh1  = d_in[18];
  const void* bih1  = d_in[19];
  const void* bhh1  = d_in[20];
  const void* outw  = d_in[21];
  const void* outb  = d_in[22];

  float* W = (float*)d_ws;
  int* flag = (int*)(W + OBAR) + 64;
  dim3 blk(256);

  k_zero<<<256, blk, 0, stream>>>(W + OBAR, ZERO_SPAN_N);
  k_zero<<<64, blk, 0, stream>>>(W + OGH0, 32768);   // dec1 initial zero
  k_detect<<<1, blk, 0, stream>>>(flag, (const u16*)pnw1);
  k_prevw<<<64, blk, 0, stream>>>(W + OPRV, dlen);
  // dual-dtype setup (wrong variant self-disables via flag)
  k_mmat<false><<<64, blk, 0, stream>>>(flag, W + OMM, alocw, aconv);
  k_mmat<true ><<<64, blk, 0, stream>>>(flag, W + OMM, alocw, aconv);
  k_cvtT512<false><<<512, blk, 0, stream>>>(flag, W + OGI0, aencw);
  k_cvtT512<true ><<<512, blk, 0, stream>>>(flag, W + OGI0, aencw);
  k_pm<false><<<2048, blk, 0, stream>>>(flag, (u16*)(W + OPM), enc, W + OGI0, aencb);
  k_pm<true ><<<2048, blk, 0, stream>>>(flag, (u16*)(W + OPM), enc, W + OGI0, aencb);

  KP kp;
  kp.enc = enc; kp.dlen = dlen;
  kp.pm = (const u16*)(W + OPM);
  kp.wih0 = wih0; kp.whh0 = whh0;
  kp.wih1 = wih1; kp.whh1 = whh1;
  kp.adec = adecw; kp.outw = outw;
  kp.pnw2 = pnw2; kp.pnw1 = pnw1;
  kp.pnb1 = pnb1; kp.pnb2 = pnb2;
  kp.bih0 = bih0; kp.bhh0 = bhh0;
  kp.bih1 = bih1; kp.bhh1 = bhh1;
  kp.outb = outb; kp.vw = avw;
  kp.Mg = W + OMM;
  kp.bar = (int*)(W + OBAR);
  kp.flags = (int*)(W + OFLG);
  kp.asum = W + OASUM; kp.dec = W + ODEC;
  kp.h0T = W + OH0; kp.h1T = W + OH1; kp.poT = W + OPO;
  kp.prevw = W + OPRV; kp.erg = W + OERG;
  kp.x1T = W + OX1; kp.x2T = W + OX2; kp.attcT = W + OATTC;
  kp.gi0p = W + OGI0; kp.gh0p = W + OGH0;
  kp.gh1p = W + OGH1; kp.gi1p = W + OGI1;
  kp.out = d_out;

  // both variants launched; the wrong-dtype one exits before touching the barrier
  k_loop<false><<<dim3(256), dim3(512), 0, stream>>>(kp);
  k_loop<true ><<<dim3(256), dim3(512), 0, stream>>>(kp);
}